// Round 15
// baseline (291.213 us; speedup 1.0000x reference)
//
#include <hip/hip_runtime.h>
#include <math.h>
#include <utility>

#define B 8
#define L 4096
#define C 512          // H*DK == H*DV == 512
#define NF 4096        // FFT length == L
#define TOPK 8
#define TS 272         // padded LDS row stride (16*17)
#define CPBK 8         // channels per block in corr
#define NBLK (B * C / CPBK)   // 512 corr blocks

typedef short bf16x8 __attribute__((ext_vector_type(8)));
typedef float f32x4 __attribute__((ext_vector_type(4)));

__device__ inline unsigned short f2bf(float f) {
    unsigned int u = __float_as_uint(f);
    u += 0x7FFF + ((u >> 16) & 1);          // round-to-nearest-even
    return (unsigned short)(u >> 16);
}
__device__ inline float bf2f(unsigned short h) {
    return __uint_as_float(((unsigned int)h) << 16);
}

__device__ inline void gload_lds16(const void* g, void* l) {
    __builtin_amdgcn_global_load_lds(
        (const __attribute__((address_space(1))) void*)g,
        (__attribute__((address_space(3))) void*)l, 16, 0, 0);
}

// ---------------------------------------------------------------------------
// f32 -> bf16 for the 3 square weights in one launch (z selects tensor)
// ---------------------------------------------------------------------------
__global__ __launch_bounds__(256) void cvt_bf16_3(const float4* __restrict__ i0,
                                                  uint4* __restrict__ o0,
                                                  const float4* __restrict__ i1,
                                                  uint4* __restrict__ o1,
                                                  const float4* __restrict__ i2,
                                                  uint4* __restrict__ o2) {
    const float4* in = blockIdx.z == 0 ? i0 : (blockIdx.z == 1 ? i1 : i2);
    uint4* out       = blockIdx.z == 0 ? o0 : (blockIdx.z == 1 ? o1 : o2);
    const int gid = blockIdx.x * 256 + threadIdx.x;
    const float4 a = in[gid * 2];
    const float4 b = in[gid * 2 + 1];
    uint4 o;
    o.x = (unsigned)f2bf(a.x) | ((unsigned)f2bf(a.y) << 16);
    o.y = (unsigned)f2bf(a.z) | ((unsigned)f2bf(a.w) << 16);
    o.z = (unsigned)f2bf(b.x) | ((unsigned)f2bf(b.y) << 16);
    o.w = (unsigned)f2bf(b.z) | ((unsigned)f2bf(b.w) << 16);
    out[gid] = o;
}

// ---------------------------------------------------------------------------
// ktrans body: one 64x64 tile of K (B,L,512 f32) -> kTb (B,512,L bf16)
// ---------------------------------------------------------------------------
__device__ __forceinline__ void ktrans_body(float* tile,   // [64][65]
                                            const float* __restrict__ Kin,
                                            unsigned short* __restrict__ kTb,
                                            int t0, int c0, int b) {
    const int tid = threadIdx.x;
    const int tc = tid & 63, tr = tid >> 6;
#pragma unroll
    for (int i = 0; i < 16; ++i) {
        const int r = tr + i * 4;
        tile[r * 65 + tc] = Kin[((size_t)(b * 4096) + t0 + r) * 512 + c0 + tc];
    }
    __syncthreads();
#pragma unroll
    for (int i = 0; i < 16; ++i) {
        const int cc = tr + i * 4;
        kTb[((size_t)(b * 512) + c0 + cc) * 4096 + t0 + tc] = f2bf(tile[tc * 65 + cc]);
    }
}

// ---------------------------------------------------------------------------
// W (512x512 f32, K x N) -> Wt (N x K, bf16), 32x32 LDS tiles
// ---------------------------------------------------------------------------
__global__ __launch_bounds__(256) void wtrans(const float* __restrict__ W,
                                              unsigned short* __restrict__ Wt) {
    __shared__ float t[32][33];
    const int tx = threadIdx.x & 31, ty = threadIdx.x >> 5;   // 32 x 8
    const int bx = blockIdx.x;   // N tile
    const int by = blockIdx.y;   // K tile
#pragma unroll
    for (int i = 0; i < 4; ++i) {
        const int k = by * 32 + ty + i * 8;
        t[ty + i * 8][tx] = W[(size_t)k * 512 + bx * 32 + tx];   // t[k][n]
    }
    __syncthreads();
#pragma unroll
    for (int i = 0; i < 4; ++i) {
        const int n = bx * 32 + ty + i * 8;
        Wt[(size_t)n * 512 + by * 32 + tx] = f2bf(t[tx][ty + i * 8]);
    }
}

// ---------------------------------------------------------------------------
// Shared GEMM tile body: C[128x128] at (row0, col0) = A * Bt^T over K=512.
// F32A=1: A f32, cast fused into reg-staged A (same LDS layout).
// TRANSOUT=1: bf16 out at [(b*512+col)*4096 + t] (b = row0>>12), else
// row-major bf16.
// ---------------------------------------------------------------------------
template <int TRANSOUT, int F32A>
__device__ __forceinline__ void gemm_body(unsigned short* Asm, unsigned short* Bsm,
                                          const void* __restrict__ Ap,
                                          const unsigned short* __restrict__ Bt,
                                          void* __restrict__ OutP,
                                          int row0, int col0) {
    const int tid = threadIdx.x;
    const int lane = tid & 63;
    const int w = tid >> 6;
    const int wr = w >> 1, wc = w & 1;

    const int ldr = tid >> 3;            // 0..31: row within 32-row group
    const int ldk = (tid & 7) << 3;      // k offset (8 elems per lane)
    const int ldsbase = (w << 3) * 64;   // wave's 8-row base within group

    f32x4 acc[4][4] = {};

    for (int k0 = 0; k0 < 512; k0 += 64) {
        __syncthreads();
#pragma unroll
        for (int i = 0; i < 4; ++i) {
            if (F32A) {
                const float* Af = (const float*)Ap;
                const size_t base = (size_t)(row0 + i * 32 + ldr) * 512 + k0 + ldk;
                const float4 v0 = *(const float4*)&Af[base];
                const float4 v1 = *(const float4*)&Af[base + 4];
                ushort4 u0, u1;
                u0.x = f2bf(v0.x); u0.y = f2bf(v0.y); u0.z = f2bf(v0.z); u0.w = f2bf(v0.w);
                u1.x = f2bf(v1.x); u1.y = f2bf(v1.y); u1.z = f2bf(v1.z); u1.w = f2bf(v1.w);
                *(ushort4*)&Asm[i * 2048 + ldr * 64 + ldk]     = u0;
                *(ushort4*)&Asm[i * 2048 + ldr * 64 + ldk + 4] = u1;
            } else {
                gload_lds16((const unsigned short*)Ap +
                                (size_t)(row0 + i * 32 + ldr) * 512 + k0 + ldk,
                            Asm + i * 32 * 64 + ldsbase);
            }
            gload_lds16(Bt + (size_t)(col0 + i * 32 + ldr) * 512 + k0 + ldk,
                        Bsm + i * 32 * 64 + ldsbase);
        }
        __syncthreads();
#pragma unroll
        for (int kk = 0; kk < 2; ++kk) {
            bf16x8 af[4], bfv[4];
#pragma unroll
            for (int m = 0; m < 4; ++m)
                af[m] = *(const bf16x8*)&Asm[(wr * 64 + m * 16 + (lane & 15)) * 64 +
                                             kk * 32 + (lane >> 4) * 8];
#pragma unroll
            for (int n = 0; n < 4; ++n)
                bfv[n] = *(const bf16x8*)&Bsm[(wc * 64 + n * 16 + (lane & 15)) * 64 +
                                              kk * 32 + (lane >> 4) * 8];
#pragma unroll
            for (int m = 0; m < 4; ++m)
#pragma unroll
                for (int n = 0; n < 4; ++n)
                    acc[m][n] = __builtin_amdgcn_mfma_f32_16x16x32_bf16(
                        af[m], bfv[n], acc[m][n], 0, 0, 0);
        }
    }

    if (TRANSOUT) {
        unsigned short* Out = (unsigned short*)OutP;
        const int bidx = row0 >> 12;
        const int t0base = (row0 & 4095) + wr * 64 + (lane >> 4) * 4;
#pragma unroll
        for (int n = 0; n < 4; ++n) {
            const int col = col0 + wc * 64 + n * 16 + (lane & 15);
#pragma unroll
            for (int m = 0; m < 4; ++m) {
                const int t0 = t0base + m * 16;
                ushort4 v;
                v.x = f2bf(acc[m][n][0]);
                v.y = f2bf(acc[m][n][1]);
                v.z = f2bf(acc[m][n][2]);
                v.w = f2bf(acc[m][n][3]);
                *(ushort4*)&Out[((size_t)(bidx * 512 + col)) * 4096 + t0] = v;
            }
        }
    } else {
#pragma unroll
        for (int m = 0; m < 4; ++m) {
            const int rbase = row0 + wr * 64 + m * 16 + (lane >> 4) * 4;
#pragma unroll
            for (int n = 0; n < 4; ++n) {
                const int col = col0 + wc * 64 + n * 16 + (lane & 15);
#pragma unroll
                for (int j = 0; j < 4; ++j)
                    ((unsigned short*)OutP)[(size_t)(rbase + j) * 512 + col] =
                        f2bf(acc[m][n][j]);
            }
        }
    }
}

// both 512x512 mini-GEMMs in one launch; blockIdx.z selects the operand set
__global__ __launch_bounds__(256) void gemm_mini2(const unsigned short* __restrict__ A0,
                                                  const unsigned short* __restrict__ B0,
                                                  unsigned short* __restrict__ O0,
                                                  const unsigned short* __restrict__ A1,
                                                  const unsigned short* __restrict__ B1,
                                                  unsigned short* __restrict__ O1) {
    __shared__ __align__(16) unsigned short Asm[128 * 64];
    __shared__ __align__(16) unsigned short Bsm[128 * 64];
    const unsigned short* Ap = blockIdx.z ? A1 : A0;
    const unsigned short* Bt = blockIdx.z ? B1 : B0;
    unsigned short* Out      = blockIdx.z ? O1 : O0;
    gemm_body<0, 0>(Asm, Bsm, Ap, Bt, Out, blockIdx.x * 128, blockIdx.y * 128);
}

// ===========================================================================
// Register DFT-16 machinery (radix-4 DIF, compile-time twiddles in W64 units)
// ===========================================================================
constexpr double d_sin_t(double x) {
    double t = x, s = x; const double x2 = x * x;
    for (int i = 1; i < 10; ++i) { t *= -x2 / ((2.0 * i) * (2.0 * i + 1.0)); s += t; }
    return s;
}
constexpr double d_cos_t(double x) {
    double t = 1.0, s = 1.0; const double x2 = x * x;
    for (int i = 1; i < 10; ++i) { t *= -x2 / ((2.0 * i - 1.0) * (2.0 * i)); s += t; }
    return s;
}
struct TwTab {
    float c[64]; float s[64];
    constexpr TwTab() : c{}, s{} {
        for (int j = 0; j < 64; ++j) {
            const int q = j >> 4, r = j & 15;
            const double x = 6.283185307179586476925286766559 * r / 64.0;
            const double cc = d_cos_t(x), ss = d_sin_t(x);
            double cv, sv;
            if (q == 0)      { cv =  cc; sv =  ss; }
            else if (q == 1) { cv = -ss; sv =  cc; }
            else if (q == 2) { cv = -cc; sv = -ss; }
            else             { cv =  ss; sv = -cc; }
            c[j] = (float)cv; s[j] = (float)sv;
        }
    }
};
constexpr TwTab TW;

__device__ __host__ constexpr int perm16(int p) {    // reverse 2 base-4 digits
    return ((p & 3) << 2) | ((p >> 2) & 3);
}

template <int E, int SGN>
__device__ __forceinline__ void twmul(float& xr, float& xi) {
    if constexpr ((E & 63) != 0) {
        constexpr float wc = TW.c[E & 63];
        constexpr float ws = (SGN < 0) ? -TW.s[E & 63] : TW.s[E & 63];
        const float r  = xr * wc - xi * ws;
        const float i2 = xr * ws + xi * wc;
        xr = r; xi = i2;
    }
}

template <int E1, int E2, int E3, int SGN>
__device__ __forceinline__ void bf4(float& ar, float& ai, float& br, float& bi,
                                    float& cr, float& ci, float& er, float& ei) {
    const float t0r = ar + cr, t0i = ai + ci, t1r = ar - cr, t1i = ai - ci;
    const float t2r = br + er, t2i = bi + ei, t3r = br - er, t3i = bi - ei;
    ar = t0r + t2r; ai = t0i + t2i;
    float x2r = t0r - t2r, x2i = t0i - t2i;
    float x1r, x1i, x3r, x3i;
    if (SGN < 0) { x1r = t1r + t3i; x1i = t1i - t3r; x3r = t1r - t3i; x3i = t1i + t3r; }
    else         { x1r = t1r - t3i; x1i = t1i + t3r; x3r = t1r + t3i; x3i = t1i - t3r; }
    twmul<E1, SGN>(x1r, x1i);
    twmul<E2, SGN>(x2r, x2i);
    twmul<E3, SGN>(x3r, x3i);
    br = x1r; bi = x1i;
    cr = x2r; ci = x2i;
    er = x3r; ei = x3i;
}

template <int SGN, int... Is>
__device__ __forceinline__ void fft16_s0(float* dr, float* di, std::integer_sequence<int, Is...>) {
    (bf4<4 * Is, 8 * Is, 12 * Is, SGN>(dr[Is], di[Is], dr[Is + 4], di[Is + 4],
                                       dr[Is + 8], di[Is + 8], dr[Is + 12], di[Is + 12]), ...);
}
template <int SGN, int... Is>
__device__ __forceinline__ void fft16_s1(float* dr, float* di, std::integer_sequence<int, Is...>) {
    (bf4<0, 0, 0, SGN>(dr[4 * Is], di[4 * Is], dr[4 * Is + 1], di[4 * Is + 1],
                       dr[4 * Is + 2], di[4 * Is + 2], dr[4 * Is + 3], di[4 * Is + 3]), ...);
}
// input d[n] natural; output d[p] = X[perm16(p)]
template <int SGN>
__device__ __forceinline__ void fft16r(float* dr, float* di) {
    fft16_s0<SGN>(dr, di, std::make_integer_sequence<int, 4>{});
    fft16_s1<SGN>(dr, di, std::make_integer_sequence<int, 4>{});
}

// runtime twiddle by e^{SGN*2*pi*i*arev}  (arev in revolutions, exact fp32 int/2^k)
template <int SGN>
__device__ __forceinline__ void rtw(float& xr, float& xi, float arev) {
    const float f = arev - floorf(arev);
    const float s = __builtin_amdgcn_sinf(f);
    const float c = __builtin_amdgcn_cosf(f);
    float r, i2;
    if (SGN < 0) { r = xr * c + xi * s; i2 = xi * c - xr * s; }
    else         { r = xr * c - xi * s; i2 = xi * c + xr * s; }
    xr = r; xi = i2;
}

// ---------------------------------------------------------------------------
// corr body: one block = one group of CPBK channels; 256 threads cooperate
// on a 4096-pt FFT (16x16x16 Stockham), 16 elems/thread in registers,
// software-pipelined channel loads, Z^2 in registers, plain-store flush.
// z = g + i*krev_raw: sum_c (QWQ)_c x (KWK)_c = sum_e (QM)_e x K_e.
// Partial layout per block: SWIZZLED, natural freq k at
// a(k) = ((k&15)<<4)|((k>>4)&15)|(k&0xF00).
// ---------------------------------------------------------------------------
__device__ __forceinline__ void corr_body(float* tre, float* tim,
                                          const unsigned short* __restrict__ qT,
                                          const unsigned short* __restrict__ kT,
                                          float* __restrict__ Ppart,
                                          int blk) {
    const int tid = threadIdx.x;
    const int b = blk / (NBLK / B);
    const int local = blk % (NBLK / B);
    const int hi = tid >> 4, lo = tid & 15;
    const int c0 = local * CPBK;

    float dr[16], di[16], aR[16], aI[16];
    unsigned short puq[16], puk[16];
#pragma unroll
    for (int p = 0; p < 16; ++p) { aR[p] = 0.f; aI[p] = 0.f; }

    {   // prologue: load channel 0 directly
        const unsigned short* qrow = qT + ((size_t)(b * C + c0)) * L;
        const unsigned short* krow = kT + ((size_t)(b * C + c0)) * L;
#pragma unroll
        for (int n1 = 0; n1 < 16; ++n1) {
            dr[n1] = bf2f(qrow[n1 * 256 + tid]);
            di[n1] = bf2f(krow[(4096 - n1 * 256 - tid) & 4095]);
        }
    }

#pragma unroll 1
    for (int cc = 0; cc < CPBK; ++cc) {
        if (cc + 1 < CPBK) {   // issue next channel's loads (raw u16, convert later)
            const unsigned short* qrow = qT + ((size_t)(b * C + c0 + cc + 1)) * L;
            const unsigned short* krow = kT + ((size_t)(b * C + c0 + cc + 1)) * L;
#pragma unroll
            for (int n1 = 0; n1 < 16; ++n1) {
                puq[n1] = qrow[n1 * 256 + tid];
                puk[n1] = krow[(4096 - n1 * 256 - tid) & 4095];
            }
        }
        // stage 1: DFT16 over n1 (high digit), n = n1*256 + tid
        fft16r<-1>(dr, di);
#pragma unroll
        for (int p = 1; p < 16; ++p)
            rtw<-1>(dr[p], di[p], (float)(tid * perm16(p)) * (1.0f / 4096.0f));
        __syncthreads();                     // prev iteration's T2 reads done
#pragma unroll
        for (int p = 0; p < 16; ++p) {       // T1 write: y[k1][n2] @ k1*TS+m1*17+m2
            const int a = perm16(p) * TS + hi * 17 + lo;
            tre[a] = dr[p]; tim[a] = di[p];
        }
        __syncthreads();
#pragma unroll
        for (int q = 0; q < 16; ++q) {       // T1 read: thread (k1=hi, m2=lo), over m1
            const int a = hi * TS + q * 17 + lo;
            dr[q] = tre[a]; di[q] = tim[a];
        }
        fft16r<-1>(dr, di);                  // stage 2a: DFT16 over m1
#pragma unroll
        for (int p = 1; p < 16; ++p)
            rtw<-1>(dr[p], di[p], (float)(lo * perm16(p)) * (1.0f / 256.0f));
        __syncthreads();
#pragma unroll
        for (int p = 0; p < 16; ++p) {       // T2 write: z[k1][k1'][m2]
            const int a = hi * TS + perm16(p) * 17 + lo;
            tre[a] = dr[p]; tim[a] = di[p];
        }
        __syncthreads();
#pragma unroll
        for (int q = 0; q < 16; ++q) {       // T2 read: thread (k1=hi, k1'=lo), over m2
            const int a = hi * TS + lo * 17 + q;
            dr[q] = tre[a]; di[q] = tim[a];
        }
        fft16r<-1>(dr, di);                  // stage 2b: DFT16 over m2
        // k = k1 + 16*k1' + 256*perm16(p); acc reg index p (channel-invariant)
#pragma unroll
        for (int p = 0; p < 16; ++p) {
            aR[p] += dr[p] * dr[p] - di[p] * di[p];
            aI[p] += 2.0f * dr[p] * di[p];
        }
        if (cc + 1 < CPBK) {   // rotate prefetched channel into working regs
#pragma unroll
            for (int n1 = 0; n1 < 16; ++n1) {
                dr[n1] = bf2f(puq[n1]);
                di[n1] = bf2f(puk[n1]);
            }
        }
    }

    // flush: plain float2 stores, coalesced across tid; per-block partial
    float* dst = Ppart + (size_t)blk * (2 * NF);
#pragma unroll
    for (int p = 0; p < 16; ++p) {
        const int a = tid + (perm16(p) << 8);
        *(float2*)&dst[2 * a] = make_float2(aR[p], aI[p]);
    }
}

// ---------------------------------------------------------------------------
// fused_a: Q-GEMM (1024 blocks) interleaved with ktrans (4096 blocks).
// Every 5th block is GEMM. Independent inputs/outputs.
// ---------------------------------------------------------------------------
__global__ __launch_bounds__(256) void fused_a(const float* __restrict__ Q,
                                               const unsigned short* __restrict__ Mt,
                                               unsigned short* __restrict__ qTb,
                                               const float* __restrict__ Kin,
                                               unsigned short* __restrict__ kTb) {
    __shared__ __align__(16) char smem[32768];
    if (blockIdx.x % 5 == 0) {
        const int id = blockIdx.x / 5;           // 0..1023
        unsigned short* Asm = (unsigned short*)smem;
        unsigned short* Bsm = Asm + 128 * 64;
        gemm_body<1, 1>(Asm, Bsm, Q, Mt, qTb, (id & 255) * 128, (id >> 8) * 128);
    } else {
        const int id = (blockIdx.x / 5) * 4 + (blockIdx.x % 5) - 1;   // 0..4095
        ktrans_body((float*)smem, Kin, kTb,
                    (id & 63) * 64, ((id >> 6) & 7) * 64, id >> 9);
    }
}

// ---------------------------------------------------------------------------
// fused_b: corr (512 blocks, every 3rd) interleaved with Y-GEMM (1024 blocks).
// corr reads qTb/kTb -> Ppart; GEMM reads V/Nt -> Yb. Independent.
// ---------------------------------------------------------------------------
__global__ __launch_bounds__(256) void fused_b(const float* __restrict__ V,
                                               const unsigned short* __restrict__ Nt,
                                               unsigned short* __restrict__ Yb,
                                               const unsigned short* __restrict__ qT,
                                               const unsigned short* __restrict__ kT,
                                               float* __restrict__ Ppart) {
    __shared__ __align__(16) char smem[34816];
    if (blockIdx.x % 3 == 0) {
        const int blk = blockIdx.x / 3;          // 0..511
        corr_body((float*)smem, (float*)smem + 16 * TS, qT, kT, Ppart, blk);
    } else {
        const int id = (blockIdx.x / 3) * 2 + (blockIdx.x % 3) - 1;   // 0..1023
        unsigned short* Asm = (unsigned short*)smem;
        unsigned short* Bsm = Asm + 128 * 64;
        gemm_body<0, 1>(Asm, Bsm, V, Nt, Yb, (id & 255) * 128, (id >> 8) * 128);
    }
}

// ---------------------------------------------------------------------------
// reduce_pacc: Pacc[b][j] = sum_{g} Ppart[b*(NBLK/B)+g][j], j in [0, 2*NF)
// ---------------------------------------------------------------------------
__global__ __launch_bounds__(256) void reduce_pacc(const float* __restrict__ Ppart,
                                                   float* __restrict__ Pacc) {
    const int e = blockIdx.x * 256 + threadIdx.x;   // 0 .. 65535
    const int b = e >> 13;                          // 8192 floats per batch
    const int j = e & 8191;
    const float* src = Ppart + (size_t)b * (NBLK / B) * (2 * NF) + j;
    float s = 0.f;
#pragma unroll 4
    for (int g = 0; g < NBLK / B; ++g) s += src[(size_t)g * (2 * NF)];
    Pacc[e] = s;
}

// ---------------------------------------------------------------------------
// ifft_mean: same 16x16x16 structure, SGN=+1. Reads swizzled Pacc, writes
// mean_value[b][tau] natural. mean[tau] = Im(N*ifft(S))[tau] / (2*N*512).
// ---------------------------------------------------------------------------
__global__ __launch_bounds__(256) void ifft_mean(const float* __restrict__ Pacc,
                                                 float* __restrict__ mean_value) {
    __shared__ float tre[16 * TS];
    __shared__ float tim[16 * TS];
    const int tid = threadIdx.x;
    const int b = blockIdx.x;
    const int hi = tid >> 4, lo = tid & 15;
    const float* src = Pacc + (size_t)b * (2 * NF);

    float dr[16], di[16];
#pragma unroll
    for (int n1 = 0; n1 < 16; ++n1) {    // S[n1*256+tid] at swizzled a
        const int a = ((tid & 15) << 4) | (tid >> 4) | (n1 << 8);
        dr[n1] = src[2 * a]; di[n1] = src[2 * a + 1];
    }
    fft16r<1>(dr, di);
#pragma unroll
    for (int p = 1; p < 16; ++p)
        rtw<1>(dr[p], di[p], (float)(tid * perm16(p)) * (1.0f / 4096.0f));
#pragma unroll
    for (int p = 0; p < 16; ++p) {
        const int a = perm16(p) * TS + hi * 17 + lo;
        tre[a] = dr[p]; tim[a] = di[p];
    }
    __syncthreads();
#pragma unroll
    for (int q = 0; q < 16; ++q) {
        const int a = hi * TS + q * 17 + lo;
        dr[q] = tre[a]; di[q] = tim[a];
    }
    fft16r<1>(dr, di);
#pragma unroll
    for (int p = 1; p < 16; ++p)
        rtw<1>(dr[p], di[p], (float)(lo * perm16(p)) * (1.0f / 256.0f));
    __syncthreads();
#pragma unroll
    for (int p = 0; p < 16; ++p) {
        const int a = hi * TS + perm16(p) * 17 + lo;
        tre[a] = dr[p]; tim[a] = di[p];
    }
    __syncthreads();
#pragma unroll
    for (int q = 0; q < 16; ++q) {
        const int a = hi * TS + lo * 17 + q;
        dr[q] = tre[a]; di[q] = tim[a];
    }
    fft16r<1>(dr, di);

    const float scale = 1.0f / (2.0f * 4096.0f * 512.0f);
#pragma unroll
    for (int p = 0; p < 16; ++p) {
        const int k = hi + (lo << 4) + (perm16(p) << 8);
        mean_value[(size_t)b * NF + k] = di[p] * scale;
    }
}

// ---------------------------------------------------------------------------
__global__ __launch_bounds__(256) void topk_softmax(const float* __restrict__ mean_value,
                                                    int* __restrict__ idx_out,
                                                    float* __restrict__ tc_out) {
    __shared__ float mv[NF];
    __shared__ float rv[256];
    __shared__ int ri[256];
    __shared__ int sel[TOPK];
    const int tid = threadIdx.x;

    for (int j = 0; j < 16; ++j) {
        const int t = j * 256 + tid;
        float s = 0.f;
        for (int b = 0; b < B; ++b) s += mean_value[(size_t)b * NF + t];
        mv[t] = s * (1.0f / (float)B);
    }
    __syncthreads();

    for (int iter = 0; iter < TOPK; ++iter) {
        float bv = -INFINITY; int bi = NF;
        for (int j = 0; j < 16; ++j) {
            const int t = j * 256 + tid;
            const float v = mv[t];
            if (v > bv || (v == bv && t < bi)) { bv = v; bi = t; }
        }
        rv[tid] = bv; ri[tid] = bi;
        __syncthreads();
        for (int off = 128; off > 0; off >>= 1) {
            if (tid < off) {
                if (rv[tid + off] > rv[tid] ||
                    (rv[tid + off] == rv[tid] && ri[tid + off] < ri[tid])) {
                    rv[tid] = rv[tid + off]; ri[tid] = ri[tid + off];
                }
            }
            __syncthreads();
        }
        if (tid == 0) { sel[iter] = ri[0]; mv[ri[0]] = -INFINITY; }
        __syncthreads();
    }

    if (tid < B) {
        float wv[TOPK];
        float mx = -INFINITY;
        for (int i = 0; i < TOPK; ++i) {
            wv[i] = mean_value[(size_t)tid * NF + sel[i]];
            mx = fmaxf(mx, wv[i]);
        }
        float sum = 0.f;
        for (int i = 0; i < TOPK; ++i) { wv[i] = expf(wv[i] - mx); sum += wv[i]; }
        const float inv = 1.0f / sum;
        for (int i = 0; i < TOPK; ++i) tc_out[tid * TOPK + i] = wv[i] * inv;
    }
    if (tid < TOPK) idx_out[tid] = sel[tid];
}

// ---------------------------------------------------------------------------
// context_out: out[b,t,c] = sum_i tc[b][i] * Y[b,(t+idx[i])%L,c]
// Y bf16 (= V@(WV*Wfc)); out f32 (FINAL output — roll commutes with row-GEMM).
// ---------------------------------------------------------------------------
__global__ __launch_bounds__(256) void context_out(const unsigned short* __restrict__ Y,
                                                   const int* __restrict__ idx,
                                                   const float* __restrict__ tc,
                                                   float* __restrict__ out) {
    const size_t gid = (size_t)blockIdx.x * 256 + threadIdx.x;
    const int c8 = (int)(gid & 63);
    const int t  = (int)((gid >> 6) & 4095);
    const int b  = (int)(gid >> 18);

    __shared__ int sIdx[TOPK];
    __shared__ float sW[TOPK];
    if (threadIdx.x < TOPK) {
        sIdx[threadIdx.x] = idx[threadIdx.x];
        sW[threadIdx.x]   = tc[b * TOPK + threadIdx.x];
    }
    __syncthreads();

    const unsigned short* yb = Y + (size_t)b * L * C;
    float a[8] = {};
#pragma unroll
    for (int i = 0; i < TOPK; ++i) {
        const int row = (t + sIdx[i]) & (L - 1);
        const uint4 v = *(const uint4*)&yb[(size_t)row * C + c8 * 8];
        const float wgt = sW[i];
        a[0] += wgt * bf2f((unsigned short)(v.x & 0xFFFF));
        a[1] += wgt * bf2f((unsigned short)(v.x >> 16));
        a[2] += wgt * bf2f((unsigned short)(v.y & 0xFFFF));
        a[3] += wgt * bf2f((unsigned short)(v.y >> 16));
        a[4] += wgt * bf2f((unsigned short)(v.z & 0xFFFF));
        a[5] += wgt * bf2f((unsigned short)(v.z >> 16));
        a[6] += wgt * bf2f((unsigned short)(v.w & 0xFFFF));
        a[7] += wgt * bf2f((unsigned short)(v.w >> 16));
    }
    float* o = out + gid * 8;
    *(float4*)&o[0] = make_float4(a[0], a[1], a[2], a[3]);
    *(float4*)&o[4] = make_float4(a[4], a[5], a[6], a[7]);
}

// ---------------------------------------------------------------------------
extern "C" void kernel_launch(void* const* d_in, const int* in_sizes, int n_in,
                              void* d_out, int out_size, void* d_ws, size_t ws_size,
                              hipStream_t stream) {
    const float* Q   = (const float*)d_in[0];
    const float* K   = (const float*)d_in[1];
    const float* V   = (const float*)d_in[2];
    const float* WQ  = (const float*)d_in[4];
    const float* WK  = (const float*)d_in[5];
    const float* WV  = (const float*)d_in[6];
    const float* Wfc = (const float*)d_in[7];
    float* out = (float*)d_out;

    const size_t SZ = (size_t)B * L * C;          // 16,777,216 elements
    const size_t WSZ = 512 * 512;
    unsigned short* kTb  = (unsigned short*)d_ws; // 32 MB (B,C,L) raw-K bf16
    unsigned short* qTb  = kTb + SZ;              // 32 MB (B,C,L) G = Q@M
    unsigned short* Yb   = qTb + SZ;              // 32 MB (B,L,C) Y = V@(WV*Wfc)
    unsigned short* WQb  = Yb + SZ;               // 512 KB each
    unsigned short* WKb  = WQb + WSZ;
    unsigned short* WVb  = WKb + WSZ;
    unsigned short* Wfct = WVb + WSZ;             // Wfc^T (N x K)
    unsigned short* Mt   = Wfct + WSZ;            // Mt[e][d] = (WK WQ^T)[e,d]
    unsigned short* Nt   = Mt + WSZ;              // Nt[f][d] = (WV Wfc)[d,f]
    float* Ppart      = (float*)(Nt + WSZ);           // NBLK * 2*NF = 16 MB
    float* Pacc       = Ppart + (size_t)NBLK * 2 * NF; // B*2*NF (swizzled)
    float* mean_value = Pacc + (size_t)B * 2 * NF;    // B*NF
    float* tc         = mean_value + (size_t)B * NF;  // B*TOPK
    int*   idx        = (int*)(tc + B * TOPK);        // TOPK

    cvt_bf16_3<<<dim3(128, 1, 3), 256, 0, stream>>>(
        (const float4*)WQ, (uint4*)WQb,
        (const float4*)WK, (uint4*)WKb,
        (const float4*)WV, (uint4*)WVb);
    wtrans<<<dim3(16, 16), 256, 0, stream>>>(Wfc, Wfct);

    // z=0: Mt[e][d] = sum_c WK[e,c]*WQ[d,c]
    // z=1: Nt[f][d] = sum_c Wfct[f,c]*WVb[d,c] = (WV@Wfc)[d,f]
    gemm_mini2<<<dim3(4, 4, 2), 256, 0, stream>>>(WKb, WQb, Mt, Wfct, WVb, Nt);

    // Q-GEMM (G = Q@M, transposed out) overlapped with K transpose
    fused_a<<<dim3(5120), 256, 0, stream>>>(Q, Mt, qTb, K, kTb);
    // corr FFT overlapped with Y-GEMM (Y = V@N)
    fused_b<<<dim3(1536), 256, 0, stream>>>(V, Nt, Yb, qTb, kTb, Ppart);

    reduce_pacc<<<dim3(256), 256, 0, stream>>>(Ppart, Pacc);
    ifft_mean<<<dim3(B), 256, 0, stream>>>(Pacc, mean_value);
    topk_softmax<<<dim3(1), 256, 0, stream>>>(mean_value, idx, tc);

    context_out<<<dim3(8192), 256, 0, stream>>>(Yb, idx, tc, out);
}

// Round 16
// 261.838 us; speedup vs baseline: 1.1122x; 1.1122x over previous
//
#include <hip/hip_runtime.h>
#include <math.h>
#include <utility>

#define B 8
#define L 4096
#define C 512          // H*DK == H*DV == 512
#define NF 4096        // FFT length == L
#define TOPK 8
#define TS 272         // padded LDS row stride (16*17)
#define CPBK 8         // channels per block in corr
#define NBLK (B * C / CPBK)   // 512 corr blocks

typedef short bf16x8 __attribute__((ext_vector_type(8)));
typedef float f32x4 __attribute__((ext_vector_type(4)));

__device__ inline unsigned short f2bf(float f) {
    unsigned int u = __float_as_uint(f);
    u += 0x7FFF + ((u >> 16) & 1);          // round-to-nearest-even
    return (unsigned short)(u >> 16);
}
__device__ inline float bf2f(unsigned short h) {
    return __uint_as_float(((unsigned int)h) << 16);
}

__device__ inline void gload_lds16(const void* g, void* l) {
    __builtin_amdgcn_global_load_lds(
        (const __attribute__((address_space(1))) void*)g,
        (__attribute__((address_space(3))) void*)l, 16, 0, 0);
}

// ---------------------------------------------------------------------------
// f32 -> bf16 for the 3 square weights in one launch (z selects tensor)
// ---------------------------------------------------------------------------
__global__ __launch_bounds__(256) void cvt_bf16_3(const float4* __restrict__ i0,
                                                  uint4* __restrict__ o0,
                                                  const float4* __restrict__ i1,
                                                  uint4* __restrict__ o1,
                                                  const float4* __restrict__ i2,
                                                  uint4* __restrict__ o2) {
    const float4* in = blockIdx.z == 0 ? i0 : (blockIdx.z == 1 ? i1 : i2);
    uint4* out       = blockIdx.z == 0 ? o0 : (blockIdx.z == 1 ? o1 : o2);
    const int gid = blockIdx.x * 256 + threadIdx.x;
    const float4 a = in[gid * 2];
    const float4 b = in[gid * 2 + 1];
    uint4 o;
    o.x = (unsigned)f2bf(a.x) | ((unsigned)f2bf(a.y) << 16);
    o.y = (unsigned)f2bf(a.z) | ((unsigned)f2bf(a.w) << 16);
    o.z = (unsigned)f2bf(b.x) | ((unsigned)f2bf(b.y) << 16);
    o.w = (unsigned)f2bf(b.z) | ((unsigned)f2bf(b.w) << 16);
    out[gid] = o;
}

// ---------------------------------------------------------------------------
// ktrans body: one 64x64 tile of K (B,L,512 f32) -> kTb (B,512,L bf16)
// ---------------------------------------------------------------------------
__device__ __forceinline__ void ktrans_body(float* tile,   // [64][65]
                                            const float* __restrict__ Kin,
                                            unsigned short* __restrict__ kTb,
                                            int t0, int c0, int b) {
    const int tid = threadIdx.x;
    const int tc = tid & 63, tr = tid >> 6;
#pragma unroll
    for (int i = 0; i < 16; ++i) {
        const int r = tr + i * 4;
        tile[r * 65 + tc] = Kin[((size_t)(b * 4096) + t0 + r) * 512 + c0 + tc];
    }
    __syncthreads();
#pragma unroll
    for (int i = 0; i < 16; ++i) {
        const int cc = tr + i * 4;
        kTb[((size_t)(b * 512) + c0 + cc) * 4096 + t0 + tc] = f2bf(tile[tc * 65 + cc]);
    }
}

// ---------------------------------------------------------------------------
// W (512x512 f32, K x N) -> Wt (N x K, bf16), 32x32 LDS tiles
// ---------------------------------------------------------------------------
__global__ __launch_bounds__(256) void wtrans(const float* __restrict__ W,
                                              unsigned short* __restrict__ Wt) {
    __shared__ float t[32][33];
    const int tx = threadIdx.x & 31, ty = threadIdx.x >> 5;   // 32 x 8
    const int bx = blockIdx.x;   // N tile
    const int by = blockIdx.y;   // K tile
#pragma unroll
    for (int i = 0; i < 4; ++i) {
        const int k = by * 32 + ty + i * 8;
        t[ty + i * 8][tx] = W[(size_t)k * 512 + bx * 32 + tx];   // t[k][n]
    }
    __syncthreads();
#pragma unroll
    for (int i = 0; i < 4; ++i) {
        const int n = bx * 32 + ty + i * 8;
        Wt[(size_t)n * 512 + by * 32 + tx] = f2bf(t[tx][ty + i * 8]);
    }
}

// ---------------------------------------------------------------------------
// Shared GEMM tile body: C[128x128] at (row0, col0) = A * Bt^T over K=512.
// F32A=1: A f32, cast fused into reg-staged A (same LDS layout).
// TRANSOUT=1: bf16 out at [(b*512+col)*4096 + t] (b = row0>>12), else
// row-major bf16.
// ---------------------------------------------------------------------------
template <int TRANSOUT, int F32A>
__device__ __forceinline__ void gemm_body(unsigned short* Asm, unsigned short* Bsm,
                                          const void* __restrict__ Ap,
                                          const unsigned short* __restrict__ Bt,
                                          void* __restrict__ OutP,
                                          int row0, int col0) {
    const int tid = threadIdx.x;
    const int lane = tid & 63;
    const int w = tid >> 6;
    const int wr = w >> 1, wc = w & 1;

    const int ldr = tid >> 3;            // 0..31: row within 32-row group
    const int ldk = (tid & 7) << 3;      // k offset (8 elems per lane)
    const int ldsbase = (w << 3) * 64;   // wave's 8-row base within group

    f32x4 acc[4][4] = {};

    for (int k0 = 0; k0 < 512; k0 += 64) {
        __syncthreads();
#pragma unroll
        for (int i = 0; i < 4; ++i) {
            if (F32A) {
                const float* Af = (const float*)Ap;
                const size_t base = (size_t)(row0 + i * 32 + ldr) * 512 + k0 + ldk;
                const float4 v0 = *(const float4*)&Af[base];
                const float4 v1 = *(const float4*)&Af[base + 4];
                ushort4 u0, u1;
                u0.x = f2bf(v0.x); u0.y = f2bf(v0.y); u0.z = f2bf(v0.z); u0.w = f2bf(v0.w);
                u1.x = f2bf(v1.x); u1.y = f2bf(v1.y); u1.z = f2bf(v1.z); u1.w = f2bf(v1.w);
                *(ushort4*)&Asm[i * 2048 + ldr * 64 + ldk]     = u0;
                *(ushort4*)&Asm[i * 2048 + ldr * 64 + ldk + 4] = u1;
            } else {
                gload_lds16((const unsigned short*)Ap +
                                (size_t)(row0 + i * 32 + ldr) * 512 + k0 + ldk,
                            Asm + i * 32 * 64 + ldsbase);
            }
            gload_lds16(Bt + (size_t)(col0 + i * 32 + ldr) * 512 + k0 + ldk,
                        Bsm + i * 32 * 64 + ldsbase);
        }
        __syncthreads();
#pragma unroll
        for (int kk = 0; kk < 2; ++kk) {
            bf16x8 af[4], bfv[4];
#pragma unroll
            for (int m = 0; m < 4; ++m)
                af[m] = *(const bf16x8*)&Asm[(wr * 64 + m * 16 + (lane & 15)) * 64 +
                                             kk * 32 + (lane >> 4) * 8];
#pragma unroll
            for (int n = 0; n < 4; ++n)
                bfv[n] = *(const bf16x8*)&Bsm[(wc * 64 + n * 16 + (lane & 15)) * 64 +
                                              kk * 32 + (lane >> 4) * 8];
#pragma unroll
            for (int m = 0; m < 4; ++m)
#pragma unroll
                for (int n = 0; n < 4; ++n)
                    acc[m][n] = __builtin_amdgcn_mfma_f32_16x16x32_bf16(
                        af[m], bfv[n], acc[m][n], 0, 0, 0);
        }
    }

    if (TRANSOUT) {
        unsigned short* Out = (unsigned short*)OutP;
        const int bidx = row0 >> 12;
        const int t0base = (row0 & 4095) + wr * 64 + (lane >> 4) * 4;
#pragma unroll
        for (int n = 0; n < 4; ++n) {
            const int col = col0 + wc * 64 + n * 16 + (lane & 15);
#pragma unroll
            for (int m = 0; m < 4; ++m) {
                const int t0 = t0base + m * 16;
                ushort4 v;
                v.x = f2bf(acc[m][n][0]);
                v.y = f2bf(acc[m][n][1]);
                v.z = f2bf(acc[m][n][2]);
                v.w = f2bf(acc[m][n][3]);
                *(ushort4*)&Out[((size_t)(bidx * 512 + col)) * 4096 + t0] = v;
            }
        }
    } else {
#pragma unroll
        for (int m = 0; m < 4; ++m) {
            const int rbase = row0 + wr * 64 + m * 16 + (lane >> 4) * 4;
#pragma unroll
            for (int n = 0; n < 4; ++n) {
                const int col = col0 + wc * 64 + n * 16 + (lane & 15);
#pragma unroll
                for (int j = 0; j < 4; ++j)
                    ((unsigned short*)OutP)[(size_t)(rbase + j) * 512 + col] =
                        f2bf(acc[m][n][j]);
            }
        }
    }
}

// dedicated big GEMM (grid = (rows, cols), row index fastest — r11 mapping)
template <int TRANSOUT, int F32A>
__global__ __launch_bounds__(256) void gemm_mfma(const void* __restrict__ Ap,
                                                 const unsigned short* __restrict__ Bt,
                                                 void* __restrict__ OutP) {
    __shared__ __align__(16) unsigned short Asm[128 * 64];
    __shared__ __align__(16) unsigned short Bsm[128 * 64];
    gemm_body<TRANSOUT, F32A>(Asm, Bsm, Ap, Bt, OutP,
                              blockIdx.x * 128, blockIdx.y * 128);
}

// both 512x512 mini-GEMMs in one launch; blockIdx.z selects the operand set
__global__ __launch_bounds__(256) void gemm_mini2(const unsigned short* __restrict__ A0,
                                                  const unsigned short* __restrict__ B0,
                                                  unsigned short* __restrict__ O0,
                                                  const unsigned short* __restrict__ A1,
                                                  const unsigned short* __restrict__ B1,
                                                  unsigned short* __restrict__ O1) {
    __shared__ __align__(16) unsigned short Asm[128 * 64];
    __shared__ __align__(16) unsigned short Bsm[128 * 64];
    const unsigned short* Ap = blockIdx.z ? A1 : A0;
    const unsigned short* Bt = blockIdx.z ? B1 : B0;
    unsigned short* Out      = blockIdx.z ? O1 : O0;
    gemm_body<0, 0>(Asm, Bsm, Ap, Bt, Out, blockIdx.x * 128, blockIdx.y * 128);
}

// ---------------------------------------------------------------------------
// fused_a: Q-GEMM (1024 blocks) interleaved with ktrans (4096 blocks).
// Every 5th block is GEMM. Independent inputs/outputs; both paths <= 32 KB
// LDS and GEMM dominates the register budget (benign union — unlike corr).
// ---------------------------------------------------------------------------
__global__ __launch_bounds__(256) void fused_a(const float* __restrict__ Q,
                                               const unsigned short* __restrict__ Mt,
                                               unsigned short* __restrict__ qTb,
                                               const float* __restrict__ Kin,
                                               unsigned short* __restrict__ kTb) {
    __shared__ __align__(16) char smem[32768];
    if (blockIdx.x % 5 == 0) {
        const int id = blockIdx.x / 5;           // 0..1023
        unsigned short* Asm = (unsigned short*)smem;
        unsigned short* Bsm = Asm + 128 * 64;
        gemm_body<1, 1>(Asm, Bsm, Q, Mt, qTb, (id & 255) * 128, (id >> 8) * 128);
    } else {
        const int id = (blockIdx.x / 5) * 4 + (blockIdx.x % 5) - 1;   // 0..4095
        ktrans_body((float*)smem, Kin, kTb,
                    (id & 63) * 64, ((id >> 6) & 7) * 64, id >> 9);
    }
}

// ===========================================================================
// Register DFT-16 machinery (radix-4 DIF, compile-time twiddles in W64 units)
// ===========================================================================
constexpr double d_sin_t(double x) {
    double t = x, s = x; const double x2 = x * x;
    for (int i = 1; i < 10; ++i) { t *= -x2 / ((2.0 * i) * (2.0 * i + 1.0)); s += t; }
    return s;
}
constexpr double d_cos_t(double x) {
    double t = 1.0, s = 1.0; const double x2 = x * x;
    for (int i = 1; i < 10; ++i) { t *= -x2 / ((2.0 * i - 1.0) * (2.0 * i)); s += t; }
    return s;
}
struct TwTab {
    float c[64]; float s[64];
    constexpr TwTab() : c{}, s{} {
        for (int j = 0; j < 64; ++j) {
            const int q = j >> 4, r = j & 15;
            const double x = 6.283185307179586476925286766559 * r / 64.0;
            const double cc = d_cos_t(x), ss = d_sin_t(x);
            double cv, sv;
            if (q == 0)      { cv =  cc; sv =  ss; }
            else if (q == 1) { cv = -ss; sv =  cc; }
            else if (q == 2) { cv = -cc; sv = -ss; }
            else             { cv =  ss; sv = -cc; }
            c[j] = (float)cv; s[j] = (float)sv;
        }
    }
};
constexpr TwTab TW;

__device__ __host__ constexpr int perm16(int p) {    // reverse 2 base-4 digits
    return ((p & 3) << 2) | ((p >> 2) & 3);
}

template <int E, int SGN>
__device__ __forceinline__ void twmul(float& xr, float& xi) {
    if constexpr ((E & 63) != 0) {
        constexpr float wc = TW.c[E & 63];
        constexpr float ws = (SGN < 0) ? -TW.s[E & 63] : TW.s[E & 63];
        const float r  = xr * wc - xi * ws;
        const float i2 = xr * ws + xi * wc;
        xr = r; xi = i2;
    }
}

template <int E1, int E2, int E3, int SGN>
__device__ __forceinline__ void bf4(float& ar, float& ai, float& br, float& bi,
                                    float& cr, float& ci, float& er, float& ei) {
    const float t0r = ar + cr, t0i = ai + ci, t1r = ar - cr, t1i = ai - ci;
    const float t2r = br + er, t2i = bi + ei, t3r = br - er, t3i = bi - ei;
    ar = t0r + t2r; ai = t0i + t2i;
    float x2r = t0r - t2r, x2i = t0i - t2i;
    float x1r, x1i, x3r, x3i;
    if (SGN < 0) { x1r = t1r + t3i; x1i = t1i - t3r; x3r = t1r - t3i; x3i = t1i + t3r; }
    else         { x1r = t1r - t3i; x1i = t1i + t3r; x3r = t1r + t3i; x3i = t1i - t3r; }
    twmul<E1, SGN>(x1r, x1i);
    twmul<E2, SGN>(x2r, x2i);
    twmul<E3, SGN>(x3r, x3i);
    br = x1r; bi = x1i;
    cr = x2r; ci = x2i;
    er = x3r; ei = x3i;
}

template <int SGN, int... Is>
__device__ __forceinline__ void fft16_s0(float* dr, float* di, std::integer_sequence<int, Is...>) {
    (bf4<4 * Is, 8 * Is, 12 * Is, SGN>(dr[Is], di[Is], dr[Is + 4], di[Is + 4],
                                       dr[Is + 8], di[Is + 8], dr[Is + 12], di[Is + 12]), ...);
}
template <int SGN, int... Is>
__device__ __forceinline__ void fft16_s1(float* dr, float* di, std::integer_sequence<int, Is...>) {
    (bf4<0, 0, 0, SGN>(dr[4 * Is], di[4 * Is], dr[4 * Is + 1], di[4 * Is + 1],
                       dr[4 * Is + 2], di[4 * Is + 2], dr[4 * Is + 3], di[4 * Is + 3]), ...);
}
// input d[n] natural; output d[p] = X[perm16(p)]
template <int SGN>
__device__ __forceinline__ void fft16r(float* dr, float* di) {
    fft16_s0<SGN>(dr, di, std::make_integer_sequence<int, 4>{});
    fft16_s1<SGN>(dr, di, std::make_integer_sequence<int, 4>{});
}

// runtime twiddle by e^{SGN*2*pi*i*arev}  (arev in revolutions, exact fp32 int/2^k)
template <int SGN>
__device__ __forceinline__ void rtw(float& xr, float& xi, float arev) {
    const float f = arev - floorf(arev);
    const float s = __builtin_amdgcn_sinf(f);
    const float c = __builtin_amdgcn_cosf(f);
    float r, i2;
    if (SGN < 0) { r = xr * c + xi * s; i2 = xi * c - xr * s; }
    else         { r = xr * c - xi * s; i2 = xi * c + xr * s; }
    xr = r; xi = i2;
}

// ---------------------------------------------------------------------------
// corr_fft16 (dedicated kernel — r14 exact): 256 threads per 4096-pt FFT
// (16x16x16 Stockham), 16 elems/thread, CPBK=8 channels pipelined, Z^2 in
// registers, plain-store flush to per-block partials. LDS = 34 KB.
// z = g + i*krev_raw: sum_c (QWQ)_c x (KWK)_c = sum_e (QM)_e x K_e.
// Partial layout per block: SWIZZLED, natural freq k at
// a(k) = ((k&15)<<4)|((k>>4)&15)|(k&0xF00).  grid = NBLK = 512.
// ---------------------------------------------------------------------------
__global__ __launch_bounds__(256) void corr_fft16(const unsigned short* __restrict__ qT,
                                                  const unsigned short* __restrict__ kT,
                                                  float* __restrict__ Ppart) {
    __shared__ float tre[16 * TS];    // 17 KB
    __shared__ float tim[16 * TS];    // 17 KB
    const int tid = threadIdx.x;
    const int b = blockIdx.x / (NBLK / B);
    const int local = blockIdx.x % (NBLK / B);
    const int hi = tid >> 4, lo = tid & 15;
    const int c0 = local * CPBK;

    float dr[16], di[16], aR[16], aI[16];
    unsigned short puq[16], puk[16];
#pragma unroll
    for (int p = 0; p < 16; ++p) { aR[p] = 0.f; aI[p] = 0.f; }

    {   // prologue: load channel 0 directly
        const unsigned short* qrow = qT + ((size_t)(b * C + c0)) * L;
        const unsigned short* krow = kT + ((size_t)(b * C + c0)) * L;
#pragma unroll
        for (int n1 = 0; n1 < 16; ++n1) {
            dr[n1] = bf2f(qrow[n1 * 256 + tid]);
            di[n1] = bf2f(krow[(4096 - n1 * 256 - tid) & 4095]);
        }
    }

#pragma unroll 1
    for (int cc = 0; cc < CPBK; ++cc) {
        if (cc + 1 < CPBK) {   // issue next channel's loads (raw u16, convert later)
            const unsigned short* qrow = qT + ((size_t)(b * C + c0 + cc + 1)) * L;
            const unsigned short* krow = kT + ((size_t)(b * C + c0 + cc + 1)) * L;
#pragma unroll
            for (int n1 = 0; n1 < 16; ++n1) {
                puq[n1] = qrow[n1 * 256 + tid];
                puk[n1] = krow[(4096 - n1 * 256 - tid) & 4095];
            }
        }
        // stage 1: DFT16 over n1 (high digit), n = n1*256 + tid
        fft16r<-1>(dr, di);
#pragma unroll
        for (int p = 1; p < 16; ++p)
            rtw<-1>(dr[p], di[p], (float)(tid * perm16(p)) * (1.0f / 4096.0f));
        __syncthreads();                     // prev iteration's T2 reads done
#pragma unroll
        for (int p = 0; p < 16; ++p) {       // T1 write: y[k1][n2] @ k1*TS+m1*17+m2
            const int a = perm16(p) * TS + hi * 17 + lo;
            tre[a] = dr[p]; tim[a] = di[p];
        }
        __syncthreads();
#pragma unroll
        for (int q = 0; q < 16; ++q) {       // T1 read: thread (k1=hi, m2=lo), over m1
            const int a = hi * TS + q * 17 + lo;
            dr[q] = tre[a]; di[q] = tim[a];
        }
        fft16r<-1>(dr, di);                  // stage 2a: DFT16 over m1
#pragma unroll
        for (int p = 1; p < 16; ++p)
            rtw<-1>(dr[p], di[p], (float)(lo * perm16(p)) * (1.0f / 256.0f));
        __syncthreads();
#pragma unroll
        for (int p = 0; p < 16; ++p) {       // T2 write: z[k1][k1'][m2]
            const int a = hi * TS + perm16(p) * 17 + lo;
            tre[a] = dr[p]; tim[a] = di[p];
        }
        __syncthreads();
#pragma unroll
        for (int q = 0; q < 16; ++q) {       // T2 read: thread (k1=hi, k1'=lo), over m2
            const int a = hi * TS + lo * 17 + q;
            dr[q] = tre[a]; di[q] = tim[a];
        }
        fft16r<-1>(dr, di);                  // stage 2b: DFT16 over m2
        // k = k1 + 16*k1' + 256*perm16(p); acc reg index p (channel-invariant)
#pragma unroll
        for (int p = 0; p < 16; ++p) {
            aR[p] += dr[p] * dr[p] - di[p] * di[p];
            aI[p] += 2.0f * dr[p] * di[p];
        }
        if (cc + 1 < CPBK) {   // rotate prefetched channel into working regs
#pragma unroll
            for (int n1 = 0; n1 < 16; ++n1) {
                dr[n1] = bf2f(puq[n1]);
                di[n1] = bf2f(puk[n1]);
            }
        }
    }

    // flush: plain float2 stores, coalesced across tid; per-block partial
    float* dst = Ppart + (size_t)blockIdx.x * (2 * NF);
#pragma unroll
    for (int p = 0; p < 16; ++p) {
        const int a = tid + (perm16(p) << 8);
        *(float2*)&dst[2 * a] = make_float2(aR[p], aI[p]);
    }
}

// ---------------------------------------------------------------------------
// reduce_pacc: Pacc[b][j] = sum_{g} Ppart[b*(NBLK/B)+g][j], j in [0, 2*NF)
// ---------------------------------------------------------------------------
__global__ __launch_bounds__(256) void reduce_pacc(const float* __restrict__ Ppart,
                                                   float* __restrict__ Pacc) {
    const int e = blockIdx.x * 256 + threadIdx.x;   // 0 .. 65535
    const int b = e >> 13;                          // 8192 floats per batch
    const int j = e & 8191;
    const float* src = Ppart + (size_t)b * (NBLK / B) * (2 * NF) + j;
    float s = 0.f;
#pragma unroll 4
    for (int g = 0; g < NBLK / B; ++g) s += src[(size_t)g * (2 * NF)];
    Pacc[e] = s;
}

// ---------------------------------------------------------------------------
// ifft_mean: same 16x16x16 structure, SGN=+1. Reads swizzled Pacc, writes
// mean_value[b][tau] natural. mean[tau] = Im(N*ifft(S))[tau] / (2*N*512).
// ---------------------------------------------------------------------------
__global__ __launch_bounds__(256) void ifft_mean(const float* __restrict__ Pacc,
                                                 float* __restrict__ mean_value) {
    __shared__ float tre[16 * TS];
    __shared__ float tim[16 * TS];
    const int tid = threadIdx.x;
    const int b = blockIdx.x;
    const int hi = tid >> 4, lo = tid & 15;
    const float* src = Pacc + (size_t)b * (2 * NF);

    float dr[16], di[16];
#pragma unroll
    for (int n1 = 0; n1 < 16; ++n1) {    // S[n1*256+tid] at swizzled a
        const int a = ((tid & 15) << 4) | (tid >> 4) | (n1 << 8);
        dr[n1] = src[2 * a]; di[n1] = src[2 * a + 1];
    }
    fft16r<1>(dr, di);
#pragma unroll
    for (int p = 1; p < 16; ++p)
        rtw<1>(dr[p], di[p], (float)(tid * perm16(p)) * (1.0f / 4096.0f));
#pragma unroll
    for (int p = 0; p < 16; ++p) {
        const int a = perm16(p) * TS + hi * 17 + lo;
        tre[a] = dr[p]; tim[a] = di[p];
    }
    __syncthreads();
#pragma unroll
    for (int q = 0; q < 16; ++q) {
        const int a = hi * TS + q * 17 + lo;
        dr[q] = tre[a]; di[q] = tim[a];
    }
    fft16r<1>(dr, di);
#pragma unroll
    for (int p = 1; p < 16; ++p)
        rtw<1>(dr[p], di[p], (float)(lo * perm16(p)) * (1.0f / 256.0f));
    __syncthreads();
#pragma unroll
    for (int p = 0; p < 16; ++p) {
        const int a = hi * TS + perm16(p) * 17 + lo;
        tre[a] = dr[p]; tim[a] = di[p];
    }
    __syncthreads();
#pragma unroll
    for (int q = 0; q < 16; ++q) {
        const int a = hi * TS + lo * 17 + q;
        dr[q] = tre[a]; di[q] = tim[a];
    }
    fft16r<1>(dr, di);

    const float scale = 1.0f / (2.0f * 4096.0f * 512.0f);
#pragma unroll
    for (int p = 0; p < 16; ++p) {
        const int k = hi + (lo << 4) + (perm16(p) << 8);
        mean_value[(size_t)b * NF + k] = di[p] * scale;
    }
}

// ---------------------------------------------------------------------------
__global__ __launch_bounds__(256) void topk_softmax(const float* __restrict__ mean_value,
                                                    int* __restrict__ idx_out,
                                                    float* __restrict__ tc_out) {
    __shared__ float mv[NF];
    __shared__ float rv[256];
    __shared__ int ri[256];
    __shared__ int sel[TOPK];
    const int tid = threadIdx.x;

    for (int j = 0; j < 16; ++j) {
        const int t = j * 256 + tid;
        float s = 0.f;
        for (int b = 0; b < B; ++b) s += mean_value[(size_t)b * NF + t];
        mv[t] = s * (1.0f / (float)B);
    }
    __syncthreads();

    for (int iter = 0; iter < TOPK; ++iter) {
        float bv = -INFINITY; int bi = NF;
        for (int j = 0; j < 16; ++j) {
            const int t = j * 256 + tid;
            const float v = mv[t];
            if (v > bv || (v == bv && t < bi)) { bv = v; bi = t; }
        }
        rv[tid] = bv; ri[tid] = bi;
        __syncthreads();
        for (int off = 128; off > 0; off >>= 1) {
            if (tid < off) {
                if (rv[tid + off] > rv[tid] ||
                    (rv[tid + off] == rv[tid] && ri[tid + off] < ri[tid])) {
                    rv[tid] = rv[tid + off]; ri[tid] = ri[tid + off];
                }
            }
            __syncthreads();
        }
        if (tid == 0) { sel[iter] = ri[0]; mv[ri[0]] = -INFINITY; }
        __syncthreads();
    }

    if (tid < B) {
        float wv[TOPK];
        float mx = -INFINITY;
        for (int i = 0; i < TOPK; ++i) {
            wv[i] = mean_value[(size_t)tid * NF + sel[i]];
            mx = fmaxf(mx, wv[i]);
        }
        float sum = 0.f;
        for (int i = 0; i < TOPK; ++i) { wv[i] = expf(wv[i] - mx); sum += wv[i]; }
        const float inv = 1.0f / sum;
        for (int i = 0; i < TOPK; ++i) tc_out[tid * TOPK + i] = wv[i] * inv;
    }
    if (tid < TOPK) idx_out[tid] = sel[tid];
}

// ---------------------------------------------------------------------------
// context_out: out[b,t,c] = sum_i tc[b][i] * Y[b,(t+idx[i])%L,c]
// Y bf16 (= V@(WV*Wfc)); out f32 (FINAL output — roll commutes with row-GEMM).
// ---------------------------------------------------------------------------
__global__ __launch_bounds__(256) void context_out(const unsigned short* __restrict__ Y,
                                                   const int* __restrict__ idx,
                                                   const float* __restrict__ tc,
                                                   float* __restrict__ out) {
    const size_t gid = (size_t)blockIdx.x * 256 + threadIdx.x;
    const int c8 = (int)(gid & 63);
    const int t  = (int)((gid >> 6) & 4095);
    const int b  = (int)(gid >> 18);

    __shared__ int sIdx[TOPK];
    __shared__ float sW[TOPK];
    if (threadIdx.x < TOPK) {
        sIdx[threadIdx.x] = idx[threadIdx.x];
        sW[threadIdx.x]   = tc[b * TOPK + threadIdx.x];
    }
    __syncthreads();

    const unsigned short* yb = Y + (size_t)b * L * C;
    float a[8] = {};
#pragma unroll
    for (int i = 0; i < TOPK; ++i) {
        const int row = (t + sIdx[i]) & (L - 1);
        const uint4 v = *(const uint4*)&yb[(size_t)row * C + c8 * 8];
        const float wgt = sW[i];
        a[0] += wgt * bf2f((unsigned short)(v.x & 0xFFFF));
        a[1] += wgt * bf2f((unsigned short)(v.x >> 16));
        a[2] += wgt * bf2f((unsigned short)(v.y & 0xFFFF));
        a[3] += wgt * bf2f((unsigned short)(v.y >> 16));
        a[4] += wgt * bf2f((unsigned short)(v.z & 0xFFFF));
        a[5] += wgt * bf2f((unsigned short)(v.z >> 16));
        a[6] += wgt * bf2f((unsigned short)(v.w & 0xFFFF));
        a[7] += wgt * bf2f((unsigned short)(v.w >> 16));
    }
    float* o = out + gid * 8;
    *(float4*)&o[0] = make_float4(a[0], a[1], a[2], a[3]);
    *(float4*)&o[4] = make_float4(a[4], a[5], a[6], a[7]);
}

// ---------------------------------------------------------------------------
extern "C" void kernel_launch(void* const* d_in, const int* in_sizes, int n_in,
                              void* d_out, int out_size, void* d_ws, size_t ws_size,
                              hipStream_t stream) {
    const float* Q   = (const float*)d_in[0];
    const float* K   = (const float*)d_in[1];
    const float* V   = (const float*)d_in[2];
    const float* WQ  = (const float*)d_in[4];
    const float* WK  = (const float*)d_in[5];
    const float* WV  = (const float*)d_in[6];
    const float* Wfc = (const float*)d_in[7];
    float* out = (float*)d_out;

    const size_t SZ = (size_t)B * L * C;          // 16,777,216 elements
    const size_t WSZ = 512 * 512;
    unsigned short* kTb  = (unsigned short*)d_ws; // 32 MB (B,C,L) raw-K bf16
    unsigned short* qTb  = kTb + SZ;              // 32 MB (B,C,L) G = Q@M
    unsigned short* Yb   = qTb + SZ;              // 32 MB (B,L,C) Y = V@(WV*Wfc)
    unsigned short* WQb  = Yb + SZ;               // 512 KB each
    unsigned short* WKb  = WQb + WSZ;
    unsigned short* WVb  = WKb + WSZ;
    unsigned short* Wfct = WVb + WSZ;             // Wfc^T (N x K)
    unsigned short* Mt   = Wfct + WSZ;            // Mt[e][d] = (WK WQ^T)[e,d]
    unsigned short* Nt   = Mt + WSZ;              // Nt[f][d] = (WV Wfc)[d,f]
    float* Ppart      = (float*)(Nt + WSZ);           // NBLK * 2*NF = 16 MB
    float* Pacc       = Ppart + (size_t)NBLK * 2 * NF; // B*2*NF (swizzled)
    float* mean_value = Pacc + (size_t)B * 2 * NF;    // B*NF
    float* tc         = mean_value + (size_t)B * NF;  // B*TOPK
    int*   idx        = (int*)(tc + B * TOPK);        // TOPK

    cvt_bf16_3<<<dim3(128, 1, 3), 256, 0, stream>>>(
        (const float4*)WQ, (uint4*)WQb,
        (const float4*)WK, (uint4*)WKb,
        (const float4*)WV, (uint4*)WVb);
    wtrans<<<dim3(16, 16), 256, 0, stream>>>(Wfc, Wfct);

    // z=0: Mt[e][d] = sum_c WK[e,c]*WQ[d,c]
    // z=1: Nt[f][d] = sum_c Wfct[f,c]*WVb[d,c] = (WV@Wfc)[d,f]
    gemm_mini2<<<dim3(4, 4, 2), 256, 0, stream>>>(WKb, WQb, Mt, Wfct, WVb, Nt);

    // Q-GEMM (G = Q@M, transposed out) overlapped with K transpose
    fused_a<<<dim3(5120), 256, 0, stream>>>(Q, Mt, qTb, K, kTb);
    // Y = V @ N, f32 A fused cast, row-major (B,L,C)  — dedicated kernel
    gemm_mfma<0, 1><<<dim3(256, 4), 256, 0, stream>>>(V, Nt, Yb);

    corr_fft16<<<dim3(NBLK), 256, 0, stream>>>(qTb, kTb, Ppart);
    reduce_pacc<<<dim3(256), 256, 0, stream>>>(Ppart, Pacc);
    ifft_mean<<<dim3(B), 256, 0, stream>>>(Pacc, mean_value);
    topk_softmax<<<dim3(1), 256, 0, stream>>>(mean_value, idx, tc);

    context_out<<<dim3(8192), 256, 0, stream>>>(Yb, idx, tc, out);
}

// Round 17
// 251.582 us; speedup vs baseline: 1.1575x; 1.0408x over previous
//
#include <hip/hip_runtime.h>
#include <math.h>
#include <utility>

#define B 8
#define L 4096
#define C 512          // H*DK == H*DV == 512
#define NF 4096        // FFT length == L
#define TOPK 8
#define TS 272         // padded LDS row stride (16*17)
#define CPBK 8         // channels per block in corr_fft16
#define NBLK (B * C / CPBK)   // 512 corr blocks

typedef short bf16x8 __attribute__((ext_vector_type(8)));
typedef float f32x4 __attribute__((ext_vector_type(4)));

__device__ inline unsigned short f2bf(float f) {
    unsigned int u = __float_as_uint(f);
    u += 0x7FFF + ((u >> 16) & 1);          // round-to-nearest-even
    return (unsigned short)(u >> 16);
}
__device__ inline float bf2f(unsigned short h) {
    return __uint_as_float(((unsigned int)h) << 16);
}

__device__ inline void gload_lds16(const void* g, void* l) {
    __builtin_amdgcn_global_load_lds(
        (const __attribute__((address_space(1))) void*)g,
        (__attribute__((address_space(3))) void*)l, 16, 0, 0);
}

// ---------------------------------------------------------------------------
// f32 -> bf16 for the 3 square weights in one launch (z selects tensor)
// ---------------------------------------------------------------------------
__global__ __launch_bounds__(256) void cvt_bf16_3(const float4* __restrict__ i0,
                                                  uint4* __restrict__ o0,
                                                  const float4* __restrict__ i1,
                                                  uint4* __restrict__ o1,
                                                  const float4* __restrict__ i2,
                                                  uint4* __restrict__ o2) {
    const float4* in = blockIdx.z == 0 ? i0 : (blockIdx.z == 1 ? i1 : i2);
    uint4* out       = blockIdx.z == 0 ? o0 : (blockIdx.z == 1 ? o1 : o2);
    const int gid = blockIdx.x * 256 + threadIdx.x;
    const float4 a = in[gid * 2];
    const float4 b = in[gid * 2 + 1];
    uint4 o;
    o.x = (unsigned)f2bf(a.x) | ((unsigned)f2bf(a.y) << 16);
    o.y = (unsigned)f2bf(a.z) | ((unsigned)f2bf(a.w) << 16);
    o.z = (unsigned)f2bf(b.x) | ((unsigned)f2bf(b.y) << 16);
    o.w = (unsigned)f2bf(b.z) | ((unsigned)f2bf(b.w) << 16);
    out[gid] = o;
}

// ---------------------------------------------------------------------------
// K (B,L,512 f32) -> kTb (B,512,L bf16) transpose; 64x64 tiles, 256 thr.
// ---------------------------------------------------------------------------
__global__ __launch_bounds__(256) void ktrans(const float* __restrict__ Kin,
                                              unsigned short* __restrict__ kTb) {
    __shared__ float tile[64][65];
    const int t0 = blockIdx.x * 64;
    const int c0 = blockIdx.y * 64;
    const int b  = blockIdx.z;
    const int tid = threadIdx.x;
    const int tc = tid & 63, tr = tid >> 6;
#pragma unroll
    for (int i = 0; i < 16; ++i) {
        const int r = tr + i * 4;
        tile[r][tc] = Kin[((size_t)(b * 4096) + t0 + r) * 512 + c0 + tc];
    }
    __syncthreads();
#pragma unroll
    for (int i = 0; i < 16; ++i) {
        const int cc = tr + i * 4;
        kTb[((size_t)(b * 512) + c0 + cc) * 4096 + t0 + tc] = f2bf(tile[tc][cc]);
    }
}

// ---------------------------------------------------------------------------
// W (512x512 f32, K x N) -> Wt (N x K, bf16), 32x32 LDS tiles
// ---------------------------------------------------------------------------
__global__ __launch_bounds__(256) void wtrans(const float* __restrict__ W,
                                              unsigned short* __restrict__ Wt) {
    __shared__ float t[32][33];
    const int tx = threadIdx.x & 31, ty = threadIdx.x >> 5;   // 32 x 8
    const int bx = blockIdx.x;   // N tile
    const int by = blockIdx.y;   // K tile
#pragma unroll
    for (int i = 0; i < 4; ++i) {
        const int k = by * 32 + ty + i * 8;
        t[ty + i * 8][tx] = W[(size_t)k * 512 + bx * 32 + tx];   // t[k][n]
    }
    __syncthreads();
#pragma unroll
    for (int i = 0; i < 4; ++i) {
        const int n = bx * 32 + ty + i * 8;
        Wt[(size_t)n * 512 + by * 32 + tx] = f2bf(t[tx][ty + i * 8]);
    }
}

// ---------------------------------------------------------------------------
// Shared GEMM tile body: C[128x128] at (row0, col0) = A * Bt^T over K=512.
// F32A=1: A f32, cast fused into reg-staged A (same LDS layout).
// TRANSOUT=1: bf16 out at [(b*512+col)*4096 + t] (b = row0>>12), else
// row-major bf16.
// ---------------------------------------------------------------------------
template <int TRANSOUT, int F32A>
__device__ __forceinline__ void gemm_body(unsigned short* Asm, unsigned short* Bsm,
                                          const void* __restrict__ Ap,
                                          const unsigned short* __restrict__ Bt,
                                          void* __restrict__ OutP,
                                          int row0, int col0) {
    const int tid = threadIdx.x;
    const int lane = tid & 63;
    const int w = tid >> 6;
    const int wr = w >> 1, wc = w & 1;

    const int ldr = tid >> 3;            // 0..31: row within 32-row group
    const int ldk = (tid & 7) << 3;      // k offset (8 elems per lane)
    const int ldsbase = (w << 3) * 64;   // wave's 8-row base within group

    f32x4 acc[4][4] = {};

    for (int k0 = 0; k0 < 512; k0 += 64) {
        __syncthreads();
#pragma unroll
        for (int i = 0; i < 4; ++i) {
            if (F32A) {
                const float* Af = (const float*)Ap;
                const size_t base = (size_t)(row0 + i * 32 + ldr) * 512 + k0 + ldk;
                const float4 v0 = *(const float4*)&Af[base];
                const float4 v1 = *(const float4*)&Af[base + 4];
                ushort4 u0, u1;
                u0.x = f2bf(v0.x); u0.y = f2bf(v0.y); u0.z = f2bf(v0.z); u0.w = f2bf(v0.w);
                u1.x = f2bf(v1.x); u1.y = f2bf(v1.y); u1.z = f2bf(v1.z); u1.w = f2bf(v1.w);
                *(ushort4*)&Asm[i * 2048 + ldr * 64 + ldk]     = u0;
                *(ushort4*)&Asm[i * 2048 + ldr * 64 + ldk + 4] = u1;
            } else {
                gload_lds16((const unsigned short*)Ap +
                                (size_t)(row0 + i * 32 + ldr) * 512 + k0 + ldk,
                            Asm + i * 32 * 64 + ldsbase);
            }
            gload_lds16(Bt + (size_t)(col0 + i * 32 + ldr) * 512 + k0 + ldk,
                        Bsm + i * 32 * 64 + ldsbase);
        }
        __syncthreads();
#pragma unroll
        for (int kk = 0; kk < 2; ++kk) {
            bf16x8 af[4], bfv[4];
#pragma unroll
            for (int m = 0; m < 4; ++m)
                af[m] = *(const bf16x8*)&Asm[(wr * 64 + m * 16 + (lane & 15)) * 64 +
                                             kk * 32 + (lane >> 4) * 8];
#pragma unroll
            for (int n = 0; n < 4; ++n)
                bfv[n] = *(const bf16x8*)&Bsm[(wc * 64 + n * 16 + (lane & 15)) * 64 +
                                              kk * 32 + (lane >> 4) * 8];
#pragma unroll
            for (int m = 0; m < 4; ++m)
#pragma unroll
                for (int n = 0; n < 4; ++n)
                    acc[m][n] = __builtin_amdgcn_mfma_f32_16x16x32_bf16(
                        af[m], bfv[n], acc[m][n], 0, 0, 0);
        }
    }

    if (TRANSOUT) {
        unsigned short* Out = (unsigned short*)OutP;
        const int bidx = row0 >> 12;
        const int t0base = (row0 & 4095) + wr * 64 + (lane >> 4) * 4;
#pragma unroll
        for (int n = 0; n < 4; ++n) {
            const int col = col0 + wc * 64 + n * 16 + (lane & 15);
#pragma unroll
            for (int m = 0; m < 4; ++m) {
                const int t0 = t0base + m * 16;
                ushort4 v;
                v.x = f2bf(acc[m][n][0]);
                v.y = f2bf(acc[m][n][1]);
                v.z = f2bf(acc[m][n][2]);
                v.w = f2bf(acc[m][n][3]);
                *(ushort4*)&Out[((size_t)(bidx * 512 + col)) * 4096 + t0] = v;
            }
        }
    } else {
#pragma unroll
        for (int m = 0; m < 4; ++m) {
            const int rbase = row0 + wr * 64 + m * 16 + (lane >> 4) * 4;
#pragma unroll
            for (int n = 0; n < 4; ++n) {
                const int col = col0 + wc * 64 + n * 16 + (lane & 15);
#pragma unroll
                for (int j = 0; j < 4; ++j)
                    ((unsigned short*)OutP)[(size_t)(rbase + j) * 512 + col] =
                        f2bf(acc[m][n][j]);
            }
        }
    }
}

// dedicated big GEMM (grid = (rows, cols), row index fastest — r11 mapping)
template <int TRANSOUT, int F32A>
__global__ __launch_bounds__(256) void gemm_mfma(const void* __restrict__ Ap,
                                                 const unsigned short* __restrict__ Bt,
                                                 void* __restrict__ OutP) {
    __shared__ __align__(16) unsigned short Asm[128 * 64];
    __shared__ __align__(16) unsigned short Bsm[128 * 64];
    gemm_body<TRANSOUT, F32A>(Asm, Bsm, Ap, Bt, OutP,
                              blockIdx.x * 128, blockIdx.y * 128);
}

// both 512x512 mini-GEMMs in one launch; blockIdx.z selects the operand set
__global__ __launch_bounds__(256) void gemm_mini2(const unsigned short* __restrict__ A0,
                                                  const unsigned short* __restrict__ B0,
                                                  unsigned short* __restrict__ O0,
                                                  const unsigned short* __restrict__ A1,
                                                  const unsigned short* __restrict__ B1,
                                                  unsigned short* __restrict__ O1) {
    __shared__ __align__(16) unsigned short Asm[128 * 64];
    __shared__ __align__(16) unsigned short Bsm[128 * 64];
    const unsigned short* Ap = blockIdx.z ? A1 : A0;
    const unsigned short* Bt = blockIdx.z ? B1 : B0;
    unsigned short* Out      = blockIdx.z ? O1 : O0;
    gemm_body<0, 0>(Asm, Bsm, Ap, Bt, Out, blockIdx.x * 128, blockIdx.y * 128);
}

// ===========================================================================
// Register DFT-16 machinery (radix-4 DIF, compile-time twiddles in W64 units)
// ===========================================================================
constexpr double d_sin_t(double x) {
    double t = x, s = x; const double x2 = x * x;
    for (int i = 1; i < 10; ++i) { t *= -x2 / ((2.0 * i) * (2.0 * i + 1.0)); s += t; }
    return s;
}
constexpr double d_cos_t(double x) {
    double t = 1.0, s = 1.0; const double x2 = x * x;
    for (int i = 1; i < 10; ++i) { t *= -x2 / ((2.0 * i - 1.0) * (2.0 * i)); s += t; }
    return s;
}
struct TwTab {
    float c[64]; float s[64];
    constexpr TwTab() : c{}, s{} {
        for (int j = 0; j < 64; ++j) {
            const int q = j >> 4, r = j & 15;
            const double x = 6.283185307179586476925286766559 * r / 64.0;
            const double cc = d_cos_t(x), ss = d_sin_t(x);
            double cv, sv;
            if (q == 0)      { cv =  cc; sv =  ss; }
            else if (q == 1) { cv = -ss; sv =  cc; }
            else if (q == 2) { cv = -cc; sv = -ss; }
            else             { cv =  ss; sv = -cc; }
            c[j] = (float)cv; s[j] = (float)sv;
        }
    }
};
constexpr TwTab TW;

__device__ __host__ constexpr int perm16(int p) {    // reverse 2 base-4 digits
    return ((p & 3) << 2) | ((p >> 2) & 3);
}

template <int E, int SGN>
__device__ __forceinline__ void twmul(float& xr, float& xi) {
    if constexpr ((E & 63) != 0) {
        constexpr float wc = TW.c[E & 63];
        constexpr float ws = (SGN < 0) ? -TW.s[E & 63] : TW.s[E & 63];
        const float r  = xr * wc - xi * ws;
        const float i2 = xr * ws + xi * wc;
        xr = r; xi = i2;
    }
}

template <int E1, int E2, int E3, int SGN>
__device__ __forceinline__ void bf4(float& ar, float& ai, float& br, float& bi,
                                    float& cr, float& ci, float& er, float& ei) {
    const float t0r = ar + cr, t0i = ai + ci, t1r = ar - cr, t1i = ai - ci;
    const float t2r = br + er, t2i = bi + ei, t3r = br - er, t3i = bi - ei;
    ar = t0r + t2r; ai = t0i + t2i;
    float x2r = t0r - t2r, x2i = t0i - t2i;
    float x1r, x1i, x3r, x3i;
    if (SGN < 0) { x1r = t1r + t3i; x1i = t1i - t3r; x3r = t1r - t3i; x3i = t1i + t3r; }
    else         { x1r = t1r - t3i; x1i = t1i + t3r; x3r = t1r + t3i; x3i = t1i - t3r; }
    twmul<E1, SGN>(x1r, x1i);
    twmul<E2, SGN>(x2r, x2i);
    twmul<E3, SGN>(x3r, x3i);
    br = x1r; bi = x1i;
    cr = x2r; ci = x2i;
    er = x3r; ei = x3i;
}

template <int SGN, int... Is>
__device__ __forceinline__ void fft16_s0(float* dr, float* di, std::integer_sequence<int, Is...>) {
    (bf4<4 * Is, 8 * Is, 12 * Is, SGN>(dr[Is], di[Is], dr[Is + 4], di[Is + 4],
                                       dr[Is + 8], di[Is + 8], dr[Is + 12], di[Is + 12]), ...);
}
template <int SGN, int... Is>
__device__ __forceinline__ void fft16_s1(float* dr, float* di, std::integer_sequence<int, Is...>) {
    (bf4<0, 0, 0, SGN>(dr[4 * Is], di[4 * Is], dr[4 * Is + 1], di[4 * Is + 1],
                       dr[4 * Is + 2], di[4 * Is + 2], dr[4 * Is + 3], di[4 * Is + 3]), ...);
}
// input d[n] natural; output d[p] = X[perm16(p)]
template <int SGN>
__device__ __forceinline__ void fft16r(float* dr, float* di) {
    fft16_s0<SGN>(dr, di, std::make_integer_sequence<int, 4>{});
    fft16_s1<SGN>(dr, di, std::make_integer_sequence<int, 4>{});
}

// runtime twiddle by e^{SGN*2*pi*i*arev}  (arev in revolutions, exact fp32 int/2^k)
template <int SGN>
__device__ __forceinline__ void rtw(float& xr, float& xi, float arev) {
    const float f = arev - floorf(arev);
    const float s = __builtin_amdgcn_sinf(f);
    const float c = __builtin_amdgcn_cosf(f);
    float r, i2;
    if (SGN < 0) { r = xr * c + xi * s; i2 = xi * c - xr * s; }
    else         { r = xr * c - xi * s; i2 = xi * c + xr * s; }
    xr = r; xi = i2;
}

// ---------------------------------------------------------------------------
// corr_fft16 (r14 exact): 256 threads per 4096-pt FFT (16x16x16 Stockham),
// 16 elems/thread, CPBK=8 channels pipelined, Z^2 in registers, plain-store
// flush to per-block partials. LDS = 34 KB. No occupancy hint (r13 lesson).
// z = g + i*krev_raw: sum_c (QWQ)_c x (KWK)_c = sum_e (QM)_e x K_e.
// Partial layout per block: SWIZZLED, natural freq k at
// a(k) = ((k&15)<<4)|((k>>4)&15)|(k&0xF00).  grid = NBLK = 512.
// ---------------------------------------------------------------------------
__global__ __launch_bounds__(256) void corr_fft16(const unsigned short* __restrict__ qT,
                                                  const unsigned short* __restrict__ kT,
                                                  float* __restrict__ Ppart) {
    __shared__ float tre[16 * TS];    // 17 KB
    __shared__ float tim[16 * TS];    // 17 KB
    const int tid = threadIdx.x;
    const int b = blockIdx.x / (NBLK / B);
    const int local = blockIdx.x % (NBLK / B);
    const int hi = tid >> 4, lo = tid & 15;
    const int c0 = local * CPBK;

    float dr[16], di[16], aR[16], aI[16];
    unsigned short puq[16], puk[16];
#pragma unroll
    for (int p = 0; p < 16; ++p) { aR[p] = 0.f; aI[p] = 0.f; }

    {   // prologue: load channel 0 directly
        const unsigned short* qrow = qT + ((size_t)(b * C + c0)) * L;
        const unsigned short* krow = kT + ((size_t)(b * C + c0)) * L;
#pragma unroll
        for (int n1 = 0; n1 < 16; ++n1) {
            dr[n1] = bf2f(qrow[n1 * 256 + tid]);
            di[n1] = bf2f(krow[(4096 - n1 * 256 - tid) & 4095]);
        }
    }

#pragma unroll 1
    for (int cc = 0; cc < CPBK; ++cc) {
        if (cc + 1 < CPBK) {   // issue next channel's loads (raw u16, convert later)
            const unsigned short* qrow = qT + ((size_t)(b * C + c0 + cc + 1)) * L;
            const unsigned short* krow = kT + ((size_t)(b * C + c0 + cc + 1)) * L;
#pragma unroll
            for (int n1 = 0; n1 < 16; ++n1) {
                puq[n1] = qrow[n1 * 256 + tid];
                puk[n1] = krow[(4096 - n1 * 256 - tid) & 4095];
            }
        }
        // stage 1: DFT16 over n1 (high digit), n = n1*256 + tid
        fft16r<-1>(dr, di);
#pragma unroll
        for (int p = 1; p < 16; ++p)
            rtw<-1>(dr[p], di[p], (float)(tid * perm16(p)) * (1.0f / 4096.0f));
        __syncthreads();                     // prev iteration's T2 reads done
#pragma unroll
        for (int p = 0; p < 16; ++p) {       // T1 write: y[k1][n2] @ k1*TS+m1*17+m2
            const int a = perm16(p) * TS + hi * 17 + lo;
            tre[a] = dr[p]; tim[a] = di[p];
        }
        __syncthreads();
#pragma unroll
        for (int q = 0; q < 16; ++q) {       // T1 read: thread (k1=hi, m2=lo), over m1
            const int a = hi * TS + q * 17 + lo;
            dr[q] = tre[a]; di[q] = tim[a];
        }
        fft16r<-1>(dr, di);                  // stage 2a: DFT16 over m1
#pragma unroll
        for (int p = 1; p < 16; ++p)
            rtw<-1>(dr[p], di[p], (float)(lo * perm16(p)) * (1.0f / 256.0f));
        __syncthreads();
#pragma unroll
        for (int p = 0; p < 16; ++p) {       // T2 write: z[k1][k1'][m2]
            const int a = hi * TS + perm16(p) * 17 + lo;
            tre[a] = dr[p]; tim[a] = di[p];
        }
        __syncthreads();
#pragma unroll
        for (int q = 0; q < 16; ++q) {       // T2 read: thread (k1=hi, k1'=lo), over m2
            const int a = hi * TS + lo * 17 + q;
            dr[q] = tre[a]; di[q] = tim[a];
        }
        fft16r<-1>(dr, di);                  // stage 2b: DFT16 over m2
        // k = k1 + 16*k1' + 256*perm16(p); acc reg index p (channel-invariant)
#pragma unroll
        for (int p = 0; p < 16; ++p) {
            aR[p] += dr[p] * dr[p] - di[p] * di[p];
            aI[p] += 2.0f * dr[p] * di[p];
        }
        if (cc + 1 < CPBK) {   // rotate prefetched channel into working regs
#pragma unroll
            for (int n1 = 0; n1 < 16; ++n1) {
                dr[n1] = bf2f(puq[n1]);
                di[n1] = bf2f(puk[n1]);
            }
        }
    }

    // flush: plain float2 stores, coalesced across tid; per-block partial
    float* dst = Ppart + (size_t)blockIdx.x * (2 * NF);
#pragma unroll
    for (int p = 0; p < 16; ++p) {
        const int a = tid + (perm16(p) << 8);
        *(float2*)&dst[2 * a] = make_float2(aR[p], aI[p]);
    }
}

// ---------------------------------------------------------------------------
// reduce_pacc: Pacc[b][j] = sum_{g} Ppart[b*(NBLK/B)+g][j], j in [0, 2*NF)
// ---------------------------------------------------------------------------
__global__ __launch_bounds__(256) void reduce_pacc(const float* __restrict__ Ppart,
                                                   float* __restrict__ Pacc) {
    const int e = blockIdx.x * 256 + threadIdx.x;   // 0 .. 65535
    const int b = e >> 13;                          // 8192 floats per batch
    const int j = e & 8191;
    const float* src = Ppart + (size_t)b * (NBLK / B) * (2 * NF) + j;
    float s = 0.f;
#pragma unroll 4
    for (int g = 0; g < NBLK / B; ++g) s += src[(size_t)g * (2 * NF)];
    Pacc[e] = s;
}

// ---------------------------------------------------------------------------
// ifft_mean: same 16x16x16 structure, SGN=+1. Reads swizzled Pacc, writes
// mean_value[b][tau] natural. mean[tau] = Im(N*ifft(S))[tau] / (2*N*512).
// ---------------------------------------------------------------------------
__global__ __launch_bounds__(256) void ifft_mean(const float* __restrict__ Pacc,
                                                 float* __restrict__ mean_value) {
    __shared__ float tre[16 * TS];
    __shared__ float tim[16 * TS];
    const int tid = threadIdx.x;
    const int b = blockIdx.x;
    const int hi = tid >> 4, lo = tid & 15;
    const float* src = Pacc + (size_t)b * (2 * NF);

    float dr[16], di[16];
#pragma unroll
    for (int n1 = 0; n1 < 16; ++n1) {    // S[n1*256+tid] at swizzled a
        const int a = ((tid & 15) << 4) | (tid >> 4) | (n1 << 8);
        dr[n1] = src[2 * a]; di[n1] = src[2 * a + 1];
    }
    fft16r<1>(dr, di);
#pragma unroll
    for (int p = 1; p < 16; ++p)
        rtw<1>(dr[p], di[p], (float)(tid * perm16(p)) * (1.0f / 4096.0f));
#pragma unroll
    for (int p = 0; p < 16; ++p) {
        const int a = perm16(p) * TS + hi * 17 + lo;
        tre[a] = dr[p]; tim[a] = di[p];
    }
    __syncthreads();
#pragma unroll
    for (int q = 0; q < 16; ++q) {
        const int a = hi * TS + q * 17 + lo;
        dr[q] = tre[a]; di[q] = tim[a];
    }
    fft16r<1>(dr, di);
#pragma unroll
    for (int p = 1; p < 16; ++p)
        rtw<1>(dr[p], di[p], (float)(lo * perm16(p)) * (1.0f / 256.0f));
    __syncthreads();
#pragma unroll
    for (int p = 0; p < 16; ++p) {
        const int a = hi * TS + perm16(p) * 17 + lo;
        tre[a] = dr[p]; tim[a] = di[p];
    }
    __syncthreads();
#pragma unroll
    for (int q = 0; q < 16; ++q) {
        const int a = hi * TS + lo * 17 + q;
        dr[q] = tre[a]; di[q] = tim[a];
    }
    fft16r<1>(dr, di);

    const float scale = 1.0f / (2.0f * 4096.0f * 512.0f);
#pragma unroll
    for (int p = 0; p < 16; ++p) {
        const int k = hi + (lo << 4) + (perm16(p) << 8);
        mean_value[(size_t)b * NF + k] = di[p] * scale;
    }
}

// ---------------------------------------------------------------------------
__global__ __launch_bounds__(256) void topk_softmax(const float* __restrict__ mean_value,
                                                    int* __restrict__ idx_out,
                                                    float* __restrict__ tc_out) {
    __shared__ float mv[NF];
    __shared__ float rv[256];
    __shared__ int ri[256];
    __shared__ int sel[TOPK];
    const int tid = threadIdx.x;

    for (int j = 0; j < 16; ++j) {
        const int t = j * 256 + tid;
        float s = 0.f;
        for (int b = 0; b < B; ++b) s += mean_value[(size_t)b * NF + t];
        mv[t] = s * (1.0f / (float)B);
    }
    __syncthreads();

    for (int iter = 0; iter < TOPK; ++iter) {
        float bv = -INFINITY; int bi = NF;
        for (int j = 0; j < 16; ++j) {
            const int t = j * 256 + tid;
            const float v = mv[t];
            if (v > bv || (v == bv && t < bi)) { bv = v; bi = t; }
        }
        rv[tid] = bv; ri[tid] = bi;
        __syncthreads();
        for (int off = 128; off > 0; off >>= 1) {
            if (tid < off) {
                if (rv[tid + off] > rv[tid] ||
                    (rv[tid + off] == rv[tid] && ri[tid + off] < ri[tid])) {
                    rv[tid] = rv[tid + off]; ri[tid] = ri[tid + off];
                }
            }
            __syncthreads();
        }
        if (tid == 0) { sel[iter] = ri[0]; mv[ri[0]] = -INFINITY; }
        __syncthreads();
    }

    if (tid < B) {
        float wv[TOPK];
        float mx = -INFINITY;
        for (int i = 0; i < TOPK; ++i) {
            wv[i] = mean_value[(size_t)tid * NF + sel[i]];
            mx = fmaxf(mx, wv[i]);
        }
        float sum = 0.f;
        for (int i = 0; i < TOPK; ++i) { wv[i] = expf(wv[i] - mx); sum += wv[i]; }
        const float inv = 1.0f / sum;
        for (int i = 0; i < TOPK; ++i) tc_out[tid * TOPK + i] = wv[i] * inv;
    }
    if (tid < TOPK) idx_out[tid] = sel[tid];
}

// ---------------------------------------------------------------------------
// context_out: out[b,t,c] = sum_i tc[b][i] * Y[b,(t+idx[i])%L,c]
// Y bf16 (= V@(WV*Wfc)); out f32 (FINAL output — roll commutes with row-GEMM).
// ---------------------------------------------------------------------------
__global__ __launch_bounds__(256) void context_out(const unsigned short* __restrict__ Y,
                                                   const int* __restrict__ idx,
                                                   const float* __restrict__ tc,
                                                   float* __restrict__ out) {
    const size_t gid = (size_t)blockIdx.x * 256 + threadIdx.x;
    const int c8 = (int)(gid & 63);
    const int t  = (int)((gid >> 6) & 4095);
    const int b  = (int)(gid >> 18);

    __shared__ int sIdx[TOPK];
    __shared__ float sW[TOPK];
    if (threadIdx.x < TOPK) {
        sIdx[threadIdx.x] = idx[threadIdx.x];
        sW[threadIdx.x]   = tc[b * TOPK + threadIdx.x];
    }
    __syncthreads();

    const unsigned short* yb = Y + (size_t)b * L * C;
    float a[8] = {};
#pragma unroll
    for (int i = 0; i < TOPK; ++i) {
        const int row = (t + sIdx[i]) & (L - 1);
        const uint4 v = *(const uint4*)&yb[(size_t)row * C + c8 * 8];
        const float wgt = sW[i];
        a[0] += wgt * bf2f((unsigned short)(v.x & 0xFFFF));
        a[1] += wgt * bf2f((unsigned short)(v.x >> 16));
        a[2] += wgt * bf2f((unsigned short)(v.y & 0xFFFF));
        a[3] += wgt * bf2f((unsigned short)(v.y >> 16));
        a[4] += wgt * bf2f((unsigned short)(v.z & 0xFFFF));
        a[5] += wgt * bf2f((unsigned short)(v.z >> 16));
        a[6] += wgt * bf2f((unsigned short)(v.w & 0xFFFF));
        a[7] += wgt * bf2f((unsigned short)(v.w >> 16));
    }
    float* o = out + gid * 8;
    *(float4*)&o[0] = make_float4(a[0], a[1], a[2], a[3]);
    *(float4*)&o[4] = make_float4(a[4], a[5], a[6], a[7]);
}

// ---------------------------------------------------------------------------
extern "C" void kernel_launch(void* const* d_in, const int* in_sizes, int n_in,
                              void* d_out, int out_size, void* d_ws, size_t ws_size,
                              hipStream_t stream) {
    const float* Q   = (const float*)d_in[0];
    const float* K   = (const float*)d_in[1];
    const float* V   = (const float*)d_in[2];
    const float* WQ  = (const float*)d_in[4];
    const float* WK  = (const float*)d_in[5];
    const float* WV  = (const float*)d_in[6];
    const float* Wfc = (const float*)d_in[7];
    float* out = (float*)d_out;

    const size_t SZ = (size_t)B * L * C;          // 16,777,216 elements
    const size_t WSZ = 512 * 512;
    unsigned short* kTb  = (unsigned short*)d_ws; // 32 MB (B,C,L) raw-K bf16
    unsigned short* qTb  = kTb + SZ;              // 32 MB (B,C,L) G = Q@M
    unsigned short* Yb   = qTb + SZ;              // 32 MB (B,L,C) Y = V@(WV*Wfc)
    unsigned short* WQb  = Yb + SZ;               // 512 KB each
    unsigned short* WKb  = WQb + WSZ;
    unsigned short* WVb  = WKb + WSZ;
    unsigned short* Wfct = WVb + WSZ;             // Wfc^T (N x K)
    unsigned short* Mt   = Wfct + WSZ;            // Mt[e][d] = (WK WQ^T)[e,d]
    unsigned short* Nt   = Mt + WSZ;              // Nt[f][d] = (WV Wfc)[d,f]
    float* Ppart      = (float*)(Nt + WSZ);           // NBLK * 2*NF = 16 MB
    float* Pacc       = Ppart + (size_t)NBLK * 2 * NF; // B*2*NF (swizzled)
    float* mean_value = Pacc + (size_t)B * 2 * NF;    // B*NF
    float* tc         = mean_value + (size_t)B * NF;  // B*TOPK
    int*   idx        = (int*)(tc + B * TOPK);        // TOPK

    cvt_bf16_3<<<dim3(128, 1, 3), 256, 0, stream>>>(
        (const float4*)WQ, (uint4*)WQb,
        (const float4*)WK, (uint4*)WKb,
        (const float4*)WV, (uint4*)WVb);
    wtrans<<<dim3(16, 16), 256, 0, stream>>>(Wfc, Wfct);
    ktrans<<<dim3(64, 8, 8), 256, 0, stream>>>(K, kTb);

    // z=0: Mt[e][d] = sum_c WK[e,c]*WQ[d,c]
    // z=1: Nt[f][d] = sum_c Wfct[f,c]*WVb[d,c] = (WV@Wfc)[d,f]
    gemm_mini2<<<dim3(4, 4, 2), 256, 0, stream>>>(WKb, WQb, Mt, Wfct, WVb, Nt);
    // G = Q @ M, f32 A fused cast, transposed output (B,C,L)
    gemm_mfma<1, 1><<<dim3(256, 4), 256, 0, stream>>>(Q, Mt, qTb);
    // Y = V @ N, f32 A fused cast, row-major (B,L,C)
    gemm_mfma<0, 1><<<dim3(256, 4), 256, 0, stream>>>(V, Nt, Yb);

    corr_fft16<<<dim3(NBLK), 256, 0, stream>>>(qTb, kTb, Ppart);
    reduce_pacc<<<dim3(256), 256, 0, stream>>>(Ppart, Pacc);
    ifft_mean<<<dim3(B), 256, 0, stream>>>(Pacc, mean_value);
    topk_softmax<<<dim3(1), 256, 0, stream>>>(mean_value, idx, tc);

    context_out<<<dim3(8192), 256, 0, stream>>>(Yb, idx, tc, out);
}

// Round 18
// 249.123 us; speedup vs baseline: 1.1690x; 1.0099x over previous
//
#include <hip/hip_runtime.h>
#include <math.h>
#include <utility>

#define B 8
#define L 4096
#define C 512          // H*DK == H*DV == 512
#define NF 4096        // FFT length == L
#define TOPK 8
#define TS 272         // padded LDS row stride (16*17)
#define CPBK 8         // channels per block in corr_fft16
#define NBLK (B * C / CPBK)   // 512 corr blocks

typedef short bf16x8 __attribute__((ext_vector_type(8)));
typedef float f32x4 __attribute__((ext_vector_type(4)));

__device__ inline unsigned short f2bf(float f) {
    unsigned int u = __float_as_uint(f);
    u += 0x7FFF + ((u >> 16) & 1);          // round-to-nearest-even
    return (unsigned short)(u >> 16);
}
__device__ inline float bf2f(unsigned short h) {
    return __uint_as_float(((unsigned int)h) << 16);
}

__device__ inline void gload_lds16(const void* g, void* l) {
    __builtin_amdgcn_global_load_lds(
        (const __attribute__((address_space(1))) void*)g,
        (__attribute__((address_space(3))) void*)l, 16, 0, 0);
}

// ---------------------------------------------------------------------------
// f32 -> bf16 for the 3 square weights in one launch (z selects tensor)
// ---------------------------------------------------------------------------
__global__ __launch_bounds__(256) void cvt_bf16_3(const float4* __restrict__ i0,
                                                  uint4* __restrict__ o0,
                                                  const float4* __restrict__ i1,
                                                  uint4* __restrict__ o1,
                                                  const float4* __restrict__ i2,
                                                  uint4* __restrict__ o2) {
    const float4* in = blockIdx.z == 0 ? i0 : (blockIdx.z == 1 ? i1 : i2);
    uint4* out       = blockIdx.z == 0 ? o0 : (blockIdx.z == 1 ? o1 : o2);
    const int gid = blockIdx.x * 256 + threadIdx.x;
    const float4 a = in[gid * 2];
    const float4 b = in[gid * 2 + 1];
    uint4 o;
    o.x = (unsigned)f2bf(a.x) | ((unsigned)f2bf(a.y) << 16);
    o.y = (unsigned)f2bf(a.z) | ((unsigned)f2bf(a.w) << 16);
    o.z = (unsigned)f2bf(b.x) | ((unsigned)f2bf(b.y) << 16);
    o.w = (unsigned)f2bf(b.z) | ((unsigned)f2bf(b.w) << 16);
    out[gid] = o;
}

// ---------------------------------------------------------------------------
// K (B,L,512 f32) -> kTb (B,512,L bf16) transpose; 64x64 tiles, 256 thr.
// ---------------------------------------------------------------------------
__global__ __launch_bounds__(256) void ktrans(const float* __restrict__ Kin,
                                              unsigned short* __restrict__ kTb) {
    __shared__ float tile[64][65];
    const int t0 = blockIdx.x * 64;
    const int c0 = blockIdx.y * 64;
    const int b  = blockIdx.z;
    const int tid = threadIdx.x;
    const int tc = tid & 63, tr = tid >> 6;
#pragma unroll
    for (int i = 0; i < 16; ++i) {
        const int r = tr + i * 4;
        tile[r][tc] = Kin[((size_t)(b * 4096) + t0 + r) * 512 + c0 + tc];
    }
    __syncthreads();
#pragma unroll
    for (int i = 0; i < 16; ++i) {
        const int cc = tr + i * 4;
        kTb[((size_t)(b * 512) + c0 + cc) * 4096 + t0 + tc] = f2bf(tile[tc][cc]);
    }
}

// ---------------------------------------------------------------------------
// W (512x512 f32, K x N) -> Wt (N x K, bf16), 32x32 LDS tiles
// ---------------------------------------------------------------------------
__global__ __launch_bounds__(256) void wtrans(const float* __restrict__ W,
                                              unsigned short* __restrict__ Wt) {
    __shared__ float t[32][33];
    const int tx = threadIdx.x & 31, ty = threadIdx.x >> 5;   // 32 x 8
    const int bx = blockIdx.x;   // N tile
    const int by = blockIdx.y;   // K tile
#pragma unroll
    for (int i = 0; i < 4; ++i) {
        const int k = by * 32 + ty + i * 8;
        t[ty + i * 8][tx] = W[(size_t)k * 512 + bx * 32 + tx];   // t[k][n]
    }
    __syncthreads();
#pragma unroll
    for (int i = 0; i < 4; ++i) {
        const int n = bx * 32 + ty + i * 8;
        Wt[(size_t)n * 512 + by * 32 + tx] = f2bf(t[tx][ty + i * 8]);
    }
}

// ---------------------------------------------------------------------------
// Shared GEMM tile body: C[128x128] at (row0, col0) = A * Bt^T over K=512.
// F32A=1: A f32, cast fused into reg-staged A (same LDS layout).
// transout (runtime, block-uniform): 1 -> bf16 out at [(b*512+col)*4096+t]
// (b = row0>>12); 0 -> row-major bf16. Hot loop identical either way.
// ---------------------------------------------------------------------------
template <int F32A>
__device__ __forceinline__ void gemm_body(unsigned short* Asm, unsigned short* Bsm,
                                          const void* __restrict__ Ap,
                                          const unsigned short* __restrict__ Bt,
                                          void* __restrict__ OutP,
                                          int row0, int col0, int transout) {
    const int tid = threadIdx.x;
    const int lane = tid & 63;
    const int w = tid >> 6;
    const int wr = w >> 1, wc = w & 1;

    const int ldr = tid >> 3;            // 0..31: row within 32-row group
    const int ldk = (tid & 7) << 3;      // k offset (8 elems per lane)
    const int ldsbase = (w << 3) * 64;   // wave's 8-row base within group

    f32x4 acc[4][4] = {};

    for (int k0 = 0; k0 < 512; k0 += 64) {
        __syncthreads();
#pragma unroll
        for (int i = 0; i < 4; ++i) {
            if (F32A) {
                const float* Af = (const float*)Ap;
                const size_t base = (size_t)(row0 + i * 32 + ldr) * 512 + k0 + ldk;
                const float4 v0 = *(const float4*)&Af[base];
                const float4 v1 = *(const float4*)&Af[base + 4];
                ushort4 u0, u1;
                u0.x = f2bf(v0.x); u0.y = f2bf(v0.y); u0.z = f2bf(v0.z); u0.w = f2bf(v0.w);
                u1.x = f2bf(v1.x); u1.y = f2bf(v1.y); u1.z = f2bf(v1.z); u1.w = f2bf(v1.w);
                *(ushort4*)&Asm[i * 2048 + ldr * 64 + ldk]     = u0;
                *(ushort4*)&Asm[i * 2048 + ldr * 64 + ldk + 4] = u1;
            } else {
                gload_lds16((const unsigned short*)Ap +
                                (size_t)(row0 + i * 32 + ldr) * 512 + k0 + ldk,
                            Asm + i * 32 * 64 + ldsbase);
            }
            gload_lds16(Bt + (size_t)(col0 + i * 32 + ldr) * 512 + k0 + ldk,
                        Bsm + i * 32 * 64 + ldsbase);
        }
        __syncthreads();
#pragma unroll
        for (int kk = 0; kk < 2; ++kk) {
            bf16x8 af[4], bfv[4];
#pragma unroll
            for (int m = 0; m < 4; ++m)
                af[m] = *(const bf16x8*)&Asm[(wr * 64 + m * 16 + (lane & 15)) * 64 +
                                             kk * 32 + (lane >> 4) * 8];
#pragma unroll
            for (int n = 0; n < 4; ++n)
                bfv[n] = *(const bf16x8*)&Bsm[(wc * 64 + n * 16 + (lane & 15)) * 64 +
                                              kk * 32 + (lane >> 4) * 8];
#pragma unroll
            for (int m = 0; m < 4; ++m)
#pragma unroll
                for (int n = 0; n < 4; ++n)
                    acc[m][n] = __builtin_amdgcn_mfma_f32_16x16x32_bf16(
                        af[m], bfv[n], acc[m][n], 0, 0, 0);
        }
    }

    if (transout) {
        unsigned short* Out = (unsigned short*)OutP;
        const int bidx = row0 >> 12;
        const int t0base = (row0 & 4095) + wr * 64 + (lane >> 4) * 4;
#pragma unroll
        for (int n = 0; n < 4; ++n) {
            const int col = col0 + wc * 64 + n * 16 + (lane & 15);
#pragma unroll
            for (int m = 0; m < 4; ++m) {
                const int t0 = t0base + m * 16;
                ushort4 v;
                v.x = f2bf(acc[m][n][0]);
                v.y = f2bf(acc[m][n][1]);
                v.z = f2bf(acc[m][n][2]);
                v.w = f2bf(acc[m][n][3]);
                *(ushort4*)&Out[((size_t)(bidx * 512 + col)) * 4096 + t0] = v;
            }
        }
    } else {
#pragma unroll
        for (int m = 0; m < 4; ++m) {
            const int rbase = row0 + wr * 64 + m * 16 + (lane >> 4) * 4;
#pragma unroll
            for (int n = 0; n < 4; ++n) {
                const int col = col0 + wc * 64 + n * 16 + (lane & 15);
#pragma unroll
                for (int j = 0; j < 4; ++j)
                    ((unsigned short*)OutP)[(size_t)(rbase + j) * 512 + col] =
                        f2bf(acc[m][n][j]);
            }
        }
    }
}

// ---------------------------------------------------------------------------
// gemm_big2: both 32768x512x512 GEMMs in one launch.
// z=0: G = Q @ M (f32 A fused cast, TRANSOUT)  z=1: Y = V @ N (row-major).
// Homogeneous roles: identical K-loop, LDS, staging — benign co-compilation.
// grid (256, 4, 2), row index fastest (r11 mapping).
// ---------------------------------------------------------------------------
__global__ __launch_bounds__(256) void gemm_big2(const float* __restrict__ Q,
                                                 const unsigned short* __restrict__ Mt,
                                                 unsigned short* __restrict__ qTb,
                                                 const float* __restrict__ V,
                                                 const unsigned short* __restrict__ Nt,
                                                 unsigned short* __restrict__ Yb) {
    __shared__ __align__(16) unsigned short Asm[128 * 64];
    __shared__ __align__(16) unsigned short Bsm[128 * 64];
    const int z = blockIdx.z;
    const float* Ap          = z ? V : Q;
    const unsigned short* Bt = z ? Nt : Mt;
    void* Out                = z ? (void*)Yb : (void*)qTb;
    gemm_body<1>(Asm, Bsm, Ap, Bt, Out,
                 blockIdx.x * 128, blockIdx.y * 128, z == 0);
}

// both 512x512 mini-GEMMs in one launch; blockIdx.z selects the operand set
__global__ __launch_bounds__(256) void gemm_mini2(const unsigned short* __restrict__ A0,
                                                  const unsigned short* __restrict__ B0,
                                                  unsigned short* __restrict__ O0,
                                                  const unsigned short* __restrict__ A1,
                                                  const unsigned short* __restrict__ B1,
                                                  unsigned short* __restrict__ O1) {
    __shared__ __align__(16) unsigned short Asm[128 * 64];
    __shared__ __align__(16) unsigned short Bsm[128 * 64];
    const unsigned short* Ap = blockIdx.z ? A1 : A0;
    const unsigned short* Bt = blockIdx.z ? B1 : B0;
    unsigned short* Out      = blockIdx.z ? O1 : O0;
    gemm_body<0>(Asm, Bsm, Ap, Bt, Out, blockIdx.x * 128, blockIdx.y * 128, 0);
}

// ===========================================================================
// Register DFT-16 machinery (radix-4 DIF, compile-time twiddles in W64 units)
// ===========================================================================
constexpr double d_sin_t(double x) {
    double t = x, s = x; const double x2 = x * x;
    for (int i = 1; i < 10; ++i) { t *= -x2 / ((2.0 * i) * (2.0 * i + 1.0)); s += t; }
    return s;
}
constexpr double d_cos_t(double x) {
    double t = 1.0, s = 1.0; const double x2 = x * x;
    for (int i = 1; i < 10; ++i) { t *= -x2 / ((2.0 * i - 1.0) * (2.0 * i)); s += t; }
    return s;
}
struct TwTab {
    float c[64]; float s[64];
    constexpr TwTab() : c{}, s{} {
        for (int j = 0; j < 64; ++j) {
            const int q = j >> 4, r = j & 15;
            const double x = 6.283185307179586476925286766559 * r / 64.0;
            const double cc = d_cos_t(x), ss = d_sin_t(x);
            double cv, sv;
            if (q == 0)      { cv =  cc; sv =  ss; }
            else if (q == 1) { cv = -ss; sv =  cc; }
            else if (q == 2) { cv = -cc; sv = -ss; }
            else             { cv =  ss; sv = -cc; }
            c[j] = (float)cv; s[j] = (float)sv;
        }
    }
};
constexpr TwTab TW;

__device__ __host__ constexpr int perm16(int p) {    // reverse 2 base-4 digits
    return ((p & 3) << 2) | ((p >> 2) & 3);
}

template <int E, int SGN>
__device__ __forceinline__ void twmul(float& xr, float& xi) {
    if constexpr ((E & 63) != 0) {
        constexpr float wc = TW.c[E & 63];
        constexpr float ws = (SGN < 0) ? -TW.s[E & 63] : TW.s[E & 63];
        const float r  = xr * wc - xi * ws;
        const float i2 = xr * ws + xi * wc;
        xr = r; xi = i2;
    }
}

template <int E1, int E2, int E3, int SGN>
__device__ __forceinline__ void bf4(float& ar, float& ai, float& br, float& bi,
                                    float& cr, float& ci, float& er, float& ei) {
    const float t0r = ar + cr, t0i = ai + ci, t1r = ar - cr, t1i = ai - ci;
    const float t2r = br + er, t2i = bi + ei, t3r = br - er, t3i = bi - ei;
    ar = t0r + t2r; ai = t0i + t2i;
    float x2r = t0r - t2r, x2i = t0i - t2i;
    float x1r, x1i, x3r, x3i;
    if (SGN < 0) { x1r = t1r + t3i; x1i = t1i - t3r; x3r = t1r - t3i; x3i = t1i + t3r; }
    else         { x1r = t1r - t3i; x1i = t1i + t3r; x3r = t1r + t3i; x3i = t1i - t3r; }
    twmul<E1, SGN>(x1r, x1i);
    twmul<E2, SGN>(x2r, x2i);
    twmul<E3, SGN>(x3r, x3i);
    br = x1r; bi = x1i;
    cr = x2r; ci = x2i;
    er = x3r; ei = x3i;
}

template <int SGN, int... Is>
__device__ __forceinline__ void fft16_s0(float* dr, float* di, std::integer_sequence<int, Is...>) {
    (bf4<4 * Is, 8 * Is, 12 * Is, SGN>(dr[Is], di[Is], dr[Is + 4], di[Is + 4],
                                       dr[Is + 8], di[Is + 8], dr[Is + 12], di[Is + 12]), ...);
}
template <int SGN, int... Is>
__device__ __forceinline__ void fft16_s1(float* dr, float* di, std::integer_sequence<int, Is...>) {
    (bf4<0, 0, 0, SGN>(dr[4 * Is], di[4 * Is], dr[4 * Is + 1], di[4 * Is + 1],
                       dr[4 * Is + 2], di[4 * Is + 2], dr[4 * Is + 3], di[4 * Is + 3]), ...);
}
// input d[n] natural; output d[p] = X[perm16(p)]
template <int SGN>
__device__ __forceinline__ void fft16r(float* dr, float* di) {
    fft16_s0<SGN>(dr, di, std::make_integer_sequence<int, 4>{});
    fft16_s1<SGN>(dr, di, std::make_integer_sequence<int, 4>{});
}

// runtime twiddle by e^{SGN*2*pi*i*arev}  (arev in revolutions, exact fp32 int/2^k)
template <int SGN>
__device__ __forceinline__ void rtw(float& xr, float& xi, float arev) {
    const float f = arev - floorf(arev);
    const float s = __builtin_amdgcn_sinf(f);
    const float c = __builtin_amdgcn_cosf(f);
    float r, i2;
    if (SGN < 0) { r = xr * c + xi * s; i2 = xi * c - xr * s; }
    else         { r = xr * c - xi * s; i2 = xi * c + xr * s; }
    xr = r; xi = i2;
}

// ---------------------------------------------------------------------------
// corr_fft16 (r14 exact): 256 threads per 4096-pt FFT (16x16x16 Stockham),
// 16 elems/thread, CPBK=8 channels pipelined, Z^2 in registers, plain-store
// flush to per-block partials. LDS = 34 KB. No occupancy hint (r13 lesson).
// z = g + i*krev_raw: sum_c (QWQ)_c x (KWK)_c = sum_e (QM)_e x K_e.
// Partial layout per block: SWIZZLED, natural freq k at
// a(k) = ((k&15)<<4)|((k>>4)&15)|(k&0xF00).  grid = NBLK = 512.
// ---------------------------------------------------------------------------
__global__ __launch_bounds__(256) void corr_fft16(const unsigned short* __restrict__ qT,
                                                  const unsigned short* __restrict__ kT,
                                                  float* __restrict__ Ppart) {
    __shared__ float tre[16 * TS];    // 17 KB
    __shared__ float tim[16 * TS];    // 17 KB
    const int tid = threadIdx.x;
    const int b = blockIdx.x / (NBLK / B);
    const int local = blockIdx.x % (NBLK / B);
    const int hi = tid >> 4, lo = tid & 15;
    const int c0 = local * CPBK;

    float dr[16], di[16], aR[16], aI[16];
    unsigned short puq[16], puk[16];
#pragma unroll
    for (int p = 0; p < 16; ++p) { aR[p] = 0.f; aI[p] = 0.f; }

    {   // prologue: load channel 0 directly
        const unsigned short* qrow = qT + ((size_t)(b * C + c0)) * L;
        const unsigned short* krow = kT + ((size_t)(b * C + c0)) * L;
#pragma unroll
        for (int n1 = 0; n1 < 16; ++n1) {
            dr[n1] = bf2f(qrow[n1 * 256 + tid]);
            di[n1] = bf2f(krow[(4096 - n1 * 256 - tid) & 4095]);
        }
    }

#pragma unroll 1
    for (int cc = 0; cc < CPBK; ++cc) {
        if (cc + 1 < CPBK) {   // issue next channel's loads (raw u16, convert later)
            const unsigned short* qrow = qT + ((size_t)(b * C + c0 + cc + 1)) * L;
            const unsigned short* krow = kT + ((size_t)(b * C + c0 + cc + 1)) * L;
#pragma unroll
            for (int n1 = 0; n1 < 16; ++n1) {
                puq[n1] = qrow[n1 * 256 + tid];
                puk[n1] = krow[(4096 - n1 * 256 - tid) & 4095];
            }
        }
        // stage 1: DFT16 over n1 (high digit), n = n1*256 + tid
        fft16r<-1>(dr, di);
#pragma unroll
        for (int p = 1; p < 16; ++p)
            rtw<-1>(dr[p], di[p], (float)(tid * perm16(p)) * (1.0f / 4096.0f));
        __syncthreads();                     // prev iteration's T2 reads done
#pragma unroll
        for (int p = 0; p < 16; ++p) {       // T1 write: y[k1][n2] @ k1*TS+m1*17+m2
            const int a = perm16(p) * TS + hi * 17 + lo;
            tre[a] = dr[p]; tim[a] = di[p];
        }
        __syncthreads();
#pragma unroll
        for (int q = 0; q < 16; ++q) {       // T1 read: thread (k1=hi, m2=lo), over m1
            const int a = hi * TS + q * 17 + lo;
            dr[q] = tre[a]; di[q] = tim[a];
        }
        fft16r<-1>(dr, di);                  // stage 2a: DFT16 over m1
#pragma unroll
        for (int p = 1; p < 16; ++p)
            rtw<-1>(dr[p], di[p], (float)(lo * perm16(p)) * (1.0f / 256.0f));
        __syncthreads();
#pragma unroll
        for (int p = 0; p < 16; ++p) {       // T2 write: z[k1][k1'][m2]
            const int a = hi * TS + perm16(p) * 17 + lo;
            tre[a] = dr[p]; tim[a] = di[p];
        }
        __syncthreads();
#pragma unroll
        for (int q = 0; q < 16; ++q) {       // T2 read: thread (k1=hi, k1'=lo), over m2
            const int a = hi * TS + lo * 17 + q;
            dr[q] = tre[a]; di[q] = tim[a];
        }
        fft16r<-1>(dr, di);                  // stage 2b: DFT16 over m2
        // k = k1 + 16*k1' + 256*perm16(p); acc reg index p (channel-invariant)
#pragma unroll
        for (int p = 0; p < 16; ++p) {
            aR[p] += dr[p] * dr[p] - di[p] * di[p];
            aI[p] += 2.0f * dr[p] * di[p];
        }
        if (cc + 1 < CPBK) {   // rotate prefetched channel into working regs
#pragma unroll
            for (int n1 = 0; n1 < 16; ++n1) {
                dr[n1] = bf2f(puq[n1]);
                di[n1] = bf2f(puk[n1]);
            }
        }
    }

    // flush: plain float2 stores, coalesced across tid; per-block partial
    float* dst = Ppart + (size_t)blockIdx.x * (2 * NF);
#pragma unroll
    for (int p = 0; p < 16; ++p) {
        const int a = tid + (perm16(p) << 8);
        *(float2*)&dst[2 * a] = make_float2(aR[p], aI[p]);
    }
}

// ---------------------------------------------------------------------------
// reduce_pacc: Pacc[b][j] = sum_{g} Ppart[b*(NBLK/B)+g][j], j in [0, 2*NF)
// ---------------------------------------------------------------------------
__global__ __launch_bounds__(256) void reduce_pacc(const float* __restrict__ Ppart,
                                                   float* __restrict__ Pacc) {
    const int e = blockIdx.x * 256 + threadIdx.x;   // 0 .. 65535
    const int b = e >> 13;                          // 8192 floats per batch
    const int j = e & 8191;
    const float* src = Ppart + (size_t)b * (NBLK / B) * (2 * NF) + j;
    float s = 0.f;
#pragma unroll 4
    for (int g = 0; g < NBLK / B; ++g) s += src[(size_t)g * (2 * NF)];
    Pacc[e] = s;
}

// ---------------------------------------------------------------------------
// ifft_mean: same 16x16x16 structure, SGN=+1. Reads swizzled Pacc, writes
// mean_value[b][tau] natural. mean[tau] = Im(N*ifft(S))[tau] / (2*N*512).
// ---------------------------------------------------------------------------
__global__ __launch_bounds__(256) void ifft_mean(const float* __restrict__ Pacc,
                                                 float* __restrict__ mean_value) {
    __shared__ float tre[16 * TS];
    __shared__ float tim[16 * TS];
    const int tid = threadIdx.x;
    const int b = blockIdx.x;
    const int hi = tid >> 4, lo = tid & 15;
    const float* src = Pacc + (size_t)b * (2 * NF);

    float dr[16], di[16];
#pragma unroll
    for (int n1 = 0; n1 < 16; ++n1) {    // S[n1*256+tid] at swizzled a
        const int a = ((tid & 15) << 4) | (tid >> 4) | (n1 << 8);
        dr[n1] = src[2 * a]; di[n1] = src[2 * a + 1];
    }
    fft16r<1>(dr, di);
#pragma unroll
    for (int p = 1; p < 16; ++p)
        rtw<1>(dr[p], di[p], (float)(tid * perm16(p)) * (1.0f / 4096.0f));
#pragma unroll
    for (int p = 0; p < 16; ++p) {
        const int a = perm16(p) * TS + hi * 17 + lo;
        tre[a] = dr[p]; tim[a] = di[p];
    }
    __syncthreads();
#pragma unroll
    for (int q = 0; q < 16; ++q) {
        const int a = hi * TS + q * 17 + lo;
        dr[q] = tre[a]; di[q] = tim[a];
    }
    fft16r<1>(dr, di);
#pragma unroll
    for (int p = 1; p < 16; ++p)
        rtw<1>(dr[p], di[p], (float)(lo * perm16(p)) * (1.0f / 256.0f));
    __syncthreads();
#pragma unroll
    for (int p = 0; p < 16; ++p) {
        const int a = hi * TS + perm16(p) * 17 + lo;
        tre[a] = dr[p]; tim[a] = di[p];
    }
    __syncthreads();
#pragma unroll
    for (int q = 0; q < 16; ++q) {
        const int a = hi * TS + lo * 17 + q;
        dr[q] = tre[a]; di[q] = tim[a];
    }
    fft16r<1>(dr, di);

    const float scale = 1.0f / (2.0f * 4096.0f * 512.0f);
#pragma unroll
    for (int p = 0; p < 16; ++p) {
        const int k = hi + (lo << 4) + (perm16(p) << 8);
        mean_value[(size_t)b * NF + k] = di[p] * scale;
    }
}

// ---------------------------------------------------------------------------
__global__ __launch_bounds__(256) void topk_softmax(const float* __restrict__ mean_value,
                                                    int* __restrict__ idx_out,
                                                    float* __restrict__ tc_out) {
    __shared__ float mv[NF];
    __shared__ float rv[256];
    __shared__ int ri[256];
    __shared__ int sel[TOPK];
    const int tid = threadIdx.x;

    for (int j = 0; j < 16; ++j) {
        const int t = j * 256 + tid;
        float s = 0.f;
        for (int b = 0; b < B; ++b) s += mean_value[(size_t)b * NF + t];
        mv[t] = s * (1.0f / (float)B);
    }
    __syncthreads();

    for (int iter = 0; iter < TOPK; ++iter) {
        float bv = -INFINITY; int bi = NF;
        for (int j = 0; j < 16; ++j) {
            const int t = j * 256 + tid;
            const float v = mv[t];
            if (v > bv || (v == bv && t < bi)) { bv = v; bi = t; }
        }
        rv[tid] = bv; ri[tid] = bi;
        __syncthreads();
        for (int off = 128; off > 0; off >>= 1) {
            if (tid < off) {
                if (rv[tid + off] > rv[tid] ||
                    (rv[tid + off] == rv[tid] && ri[tid + off] < ri[tid])) {
                    rv[tid] = rv[tid + off]; ri[tid] = ri[tid + off];
                }
            }
            __syncthreads();
        }
        if (tid == 0) { sel[iter] = ri[0]; mv[ri[0]] = -INFINITY; }
        __syncthreads();
    }

    if (tid < B) {
        float wv[TOPK];
        float mx = -INFINITY;
        for (int i = 0; i < TOPK; ++i) {
            wv[i] = mean_value[(size_t)tid * NF + sel[i]];
            mx = fmaxf(mx, wv[i]);
        }
        float sum = 0.f;
        for (int i = 0; i < TOPK; ++i) { wv[i] = expf(wv[i] - mx); sum += wv[i]; }
        const float inv = 1.0f / sum;
        for (int i = 0; i < TOPK; ++i) tc_out[tid * TOPK + i] = wv[i] * inv;
    }
    if (tid < TOPK) idx_out[tid] = sel[tid];
}

// ---------------------------------------------------------------------------
// context_out: out[b,t,c] = sum_i tc[b][i] * Y[b,(t+idx[i])%L,c]
// Y bf16 (= V@(WV*Wfc)); out f32 (FINAL output — roll commutes with row-GEMM).
// ---------------------------------------------------------------------------
__global__ __launch_bounds__(256) void context_out(const unsigned short* __restrict__ Y,
                                                   const int* __restrict__ idx,
                                                   const float* __restrict__ tc,
                                                   float* __restrict__ out) {
    const size_t gid = (size_t)blockIdx.x * 256 + threadIdx.x;
    const int c8 = (int)(gid & 63);
    const int t  = (int)((gid >> 6) & 4095);
    const int b  = (int)(gid >> 18);

    __shared__ int sIdx[TOPK];
    __shared__ float sW[TOPK];
    if (threadIdx.x < TOPK) {
        sIdx[threadIdx.x] = idx[threadIdx.x];
        sW[threadIdx.x]   = tc[b * TOPK + threadIdx.x];
    }
    __syncthreads();

    const unsigned short* yb = Y + (size_t)b * L * C;
    float a[8] = {};
#pragma unroll
    for (int i = 0; i < TOPK; ++i) {
        const int row = (t + sIdx[i]) & (L - 1);
        const uint4 v = *(const uint4*)&yb[(size_t)row * C + c8 * 8];
        const float wgt = sW[i];
        a[0] += wgt * bf2f((unsigned short)(v.x & 0xFFFF));
        a[1] += wgt * bf2f((unsigned short)(v.x >> 16));
        a[2] += wgt * bf2f((unsigned short)(v.y & 0xFFFF));
        a[3] += wgt * bf2f((unsigned short)(v.y >> 16));
        a[4] += wgt * bf2f((unsigned short)(v.z & 0xFFFF));
        a[5] += wgt * bf2f((unsigned short)(v.z >> 16));
        a[6] += wgt * bf2f((unsigned short)(v.w & 0xFFFF));
        a[7] += wgt * bf2f((unsigned short)(v.w >> 16));
    }
    float* o = out + gid * 8;
    *(float4*)&o[0] = make_float4(a[0], a[1], a[2], a[3]);
    *(float4*)&o[4] = make_float4(a[4], a[5], a[6], a[7]);
}

// ---------------------------------------------------------------------------
extern "C" void kernel_launch(void* const* d_in, const int* in_sizes, int n_in,
                              void* d_out, int out_size, void* d_ws, size_t ws_size,
                              hipStream_t stream) {
    const float* Q   = (const float*)d_in[0];
    const float* K   = (const float*)d_in[1];
    const float* V   = (const float*)d_in[2];
    const float* WQ  = (const float*)d_in[4];
    const float* WK  = (const float*)d_in[5];
    const float* WV  = (const float*)d_in[6];
    const float* Wfc = (const float*)d_in[7];
    float* out = (float*)d_out;

    const size_t SZ = (size_t)B * L * C;          // 16,777,216 elements
    const size_t WSZ = 512 * 512;
    unsigned short* kTb  = (unsigned short*)d_ws; // 32 MB (B,C,L) raw-K bf16
    unsigned short* qTb  = kTb + SZ;              // 32 MB (B,C,L) G = Q@M
    unsigned short* Yb   = qTb + SZ;              // 32 MB (B,L,C) Y = V@(WV*Wfc)
    unsigned short* WQb  = Yb + SZ;               // 512 KB each
    unsigned short* WKb  = WQb + WSZ;
    unsigned short* WVb  = WKb + WSZ;
    unsigned short* Wfct = WVb + WSZ;             // Wfc^T (N x K)
    unsigned short* Mt   = Wfct + WSZ;            // Mt[e][d] = (WK WQ^T)[e,d]
    unsigned short* Nt   = Mt + WSZ;              // Nt[f][d] = (WV Wfc)[d,f]
    float* Ppart      = (float*)(Nt + WSZ);           // NBLK * 2*NF = 16 MB
    float* Pacc       = Ppart + (size_t)NBLK * 2 * NF; // B*2*NF (swizzled)
    float* mean_value = Pacc + (size_t)B * 2 * NF;    // B*NF
    float* tc         = mean_value + (size_t)B * NF;  // B*TOPK
    int*   idx        = (int*)(tc + B * TOPK);        // TOPK

    cvt_bf16_3<<<dim3(128, 1, 3), 256, 0, stream>>>(
        (const float4*)WQ, (uint4*)WQb,
        (const float4*)WK, (uint4*)WKb,
        (const float4*)WV, (uint4*)WVb);
    wtrans<<<dim3(16, 16), 256, 0, stream>>>(Wfc, Wfct);
    ktrans<<<dim3(64, 8, 8), 256, 0, stream>>>(K, kTb);

    // z=0: Mt[e][d] = sum_c WK[e,c]*WQ[d,c]
    // z=1: Nt[f][d] = sum_c Wfct[f,c]*WVb[d,c] = (WV@Wfc)[d,f]
    gemm_mini2<<<dim3(4, 4, 2), 256, 0, stream>>>(WKb, WQb, Mt, Wfct, WVb, Nt);
    // z=0: G = Q@M (TRANSOUT)   z=1: Y = V@N (row-major) — one launch
    gemm_big2<<<dim3(256, 4, 2), 256, 0, stream>>>(Q, Mt, qTb, V, Nt, Yb);

    corr_fft16<<<dim3(NBLK), 256, 0, stream>>>(qTb, kTb, Ppart);
    reduce_pacc<<<dim3(256), 256, 0, stream>>>(Ppart, Pacc);
    ifft_mean<<<dim3(B), 256, 0, stream>>>(Pacc, mean_value);
    topk_softmax<<<dim3(1), 256, 0, stream>>>(mean_value, idx, tc);

    context_out<<<dim3(8192), 256, 0, stream>>>(Yb, idx, tc, out);
}

// Round 19
// 234.956 us; speedup vs baseline: 1.2394x; 1.0603x over previous
//
#include <hip/hip_runtime.h>
#include <math.h>
#include <utility>

#define B 8
#define L 4096
#define C 512          // H*DK == H*DV == 512
#define NF 4096        // FFT length == L
#define TOPK 8
#define TS 272         // padded LDS row stride (16*17)
#define CPBK 8         // channels per block in corr_fft16
#define NBLK (B * C / CPBK)   // 512 corr blocks

typedef short bf16x8 __attribute__((ext_vector_type(8)));
typedef float f32x4 __attribute__((ext_vector_type(4)));

__device__ inline unsigned short f2bf(float f) {
    unsigned int u = __float_as_uint(f);
    u += 0x7FFF + ((u >> 16) & 1);          // round-to-nearest-even
    return (unsigned short)(u >> 16);
}
__device__ inline float bf2f(unsigned short h) {
    return __uint_as_float(((unsigned int)h) << 16);
}

__device__ inline void gload_lds16(const void* g, void* l) {
    __builtin_amdgcn_global_load_lds(
        (const __attribute__((address_space(1))) void*)g,
        (__attribute__((address_space(3))) void*)l, 16, 0, 0);
}

// ---------------------------------------------------------------------------
// f32 -> bf16 for the 3 square weights in one launch (z selects tensor)
// ---------------------------------------------------------------------------
__global__ __launch_bounds__(256) void cvt_bf16_3(const float4* __restrict__ i0,
                                                  uint4* __restrict__ o0,
                                                  const float4* __restrict__ i1,
                                                  uint4* __restrict__ o1,
                                                  const float4* __restrict__ i2,
                                                  uint4* __restrict__ o2) {
    const float4* in = blockIdx.z == 0 ? i0 : (blockIdx.z == 1 ? i1 : i2);
    uint4* out       = blockIdx.z == 0 ? o0 : (blockIdx.z == 1 ? o1 : o2);
    const int gid = blockIdx.x * 256 + threadIdx.x;
    const float4 a = in[gid * 2];
    const float4 b = in[gid * 2 + 1];
    uint4 o;
    o.x = (unsigned)f2bf(a.x) | ((unsigned)f2bf(a.y) << 16);
    o.y = (unsigned)f2bf(a.z) | ((unsigned)f2bf(a.w) << 16);
    o.z = (unsigned)f2bf(b.x) | ((unsigned)f2bf(b.y) << 16);
    o.w = (unsigned)f2bf(b.z) | ((unsigned)f2bf(b.w) << 16);
    out[gid] = o;
}

// ---------------------------------------------------------------------------
// K (B,L,512 f32) -> kTb (B,512,L bf16) transpose; 64x64 tiles, 256 thr.
// ---------------------------------------------------------------------------
__global__ __launch_bounds__(256) void ktrans(const float* __restrict__ Kin,
                                              unsigned short* __restrict__ kTb) {
    __shared__ float tile[64][65];
    const int t0 = blockIdx.x * 64;
    const int c0 = blockIdx.y * 64;
    const int b  = blockIdx.z;
    const int tid = threadIdx.x;
    const int tc = tid & 63, tr = tid >> 6;
#pragma unroll
    for (int i = 0; i < 16; ++i) {
        const int r = tr + i * 4;
        tile[r][tc] = Kin[((size_t)(b * 4096) + t0 + r) * 512 + c0 + tc];
    }
    __syncthreads();
#pragma unroll
    for (int i = 0; i < 16; ++i) {
        const int cc = tr + i * 4;
        kTb[((size_t)(b * 512) + c0 + cc) * 4096 + t0 + tc] = f2bf(tile[tc][cc]);
    }
}

// ---------------------------------------------------------------------------
// W (512x512 f32, K x N) -> Wt (N x K, bf16), 32x32 LDS tiles
// ---------------------------------------------------------------------------
__global__ __launch_bounds__(256) void wtrans(const float* __restrict__ W,
                                              unsigned short* __restrict__ Wt) {
    __shared__ float t[32][33];
    const int tx = threadIdx.x & 31, ty = threadIdx.x >> 5;   // 32 x 8
    const int bx = blockIdx.x;   // N tile
    const int by = blockIdx.y;   // K tile
#pragma unroll
    for (int i = 0; i < 4; ++i) {
        const int k = by * 32 + ty + i * 8;
        t[ty + i * 8][tx] = W[(size_t)k * 512 + bx * 32 + tx];   // t[k][n]
    }
    __syncthreads();
#pragma unroll
    for (int i = 0; i < 4; ++i) {
        const int n = bx * 32 + ty + i * 8;
        Wt[(size_t)n * 512 + by * 32 + tx] = f2bf(t[tx][ty + i * 8]);
    }
}

// ---------------------------------------------------------------------------
// Shared GEMM tile body: C[128x128] at (row0, col0) = A * Bt^T over K=512.
// F32A=1: A f32, cast fused into reg-staged A (same LDS layout).
// transout (runtime, block-uniform): 1 -> bf16 out at [(b*512+col)*4096+t]
// (b = row0>>12); 0 -> row-major bf16. Hot loop identical either way.
// ---------------------------------------------------------------------------
template <int F32A>
__device__ __forceinline__ void gemm_body(unsigned short* Asm, unsigned short* Bsm,
                                          const void* __restrict__ Ap,
                                          const unsigned short* __restrict__ Bt,
                                          void* __restrict__ OutP,
                                          int row0, int col0, int transout) {
    const int tid = threadIdx.x;
    const int lane = tid & 63;
    const int w = tid >> 6;
    const int wr = w >> 1, wc = w & 1;

    const int ldr = tid >> 3;            // 0..31: row within 32-row group
    const int ldk = (tid & 7) << 3;      // k offset (8 elems per lane)
    const int ldsbase = (w << 3) * 64;   // wave's 8-row base within group

    f32x4 acc[4][4] = {};

    for (int k0 = 0; k0 < 512; k0 += 64) {
        __syncthreads();
#pragma unroll
        for (int i = 0; i < 4; ++i) {
            if (F32A) {
                const float* Af = (const float*)Ap;
                const size_t base = (size_t)(row0 + i * 32 + ldr) * 512 + k0 + ldk;
                const float4 v0 = *(const float4*)&Af[base];
                const float4 v1 = *(const float4*)&Af[base + 4];
                ushort4 u0, u1;
                u0.x = f2bf(v0.x); u0.y = f2bf(v0.y); u0.z = f2bf(v0.z); u0.w = f2bf(v0.w);
                u1.x = f2bf(v1.x); u1.y = f2bf(v1.y); u1.z = f2bf(v1.z); u1.w = f2bf(v1.w);
                *(ushort4*)&Asm[i * 2048 + ldr * 64 + ldk]     = u0;
                *(ushort4*)&Asm[i * 2048 + ldr * 64 + ldk + 4] = u1;
            } else {
                gload_lds16((const unsigned short*)Ap +
                                (size_t)(row0 + i * 32 + ldr) * 512 + k0 + ldk,
                            Asm + i * 32 * 64 + ldsbase);
            }
            gload_lds16(Bt + (size_t)(col0 + i * 32 + ldr) * 512 + k0 + ldk,
                        Bsm + i * 32 * 64 + ldsbase);
        }
        __syncthreads();
#pragma unroll
        for (int kk = 0; kk < 2; ++kk) {
            bf16x8 af[4], bfv[4];
#pragma unroll
            for (int m = 0; m < 4; ++m)
                af[m] = *(const bf16x8*)&Asm[(wr * 64 + m * 16 + (lane & 15)) * 64 +
                                             kk * 32 + (lane >> 4) * 8];
#pragma unroll
            for (int n = 0; n < 4; ++n)
                bfv[n] = *(const bf16x8*)&Bsm[(wc * 64 + n * 16 + (lane & 15)) * 64 +
                                              kk * 32 + (lane >> 4) * 8];
#pragma unroll
            for (int m = 0; m < 4; ++m)
#pragma unroll
                for (int n = 0; n < 4; ++n)
                    acc[m][n] = __builtin_amdgcn_mfma_f32_16x16x32_bf16(
                        af[m], bfv[n], acc[m][n], 0, 0, 0);
        }
    }

    if (transout) {
        unsigned short* Out = (unsigned short*)OutP;
        const int bidx = row0 >> 12;
        const int t0base = (row0 & 4095) + wr * 64 + (lane >> 4) * 4;
#pragma unroll
        for (int n = 0; n < 4; ++n) {
            const int col = col0 + wc * 64 + n * 16 + (lane & 15);
#pragma unroll
            for (int m = 0; m < 4; ++m) {
                const int t0 = t0base + m * 16;
                ushort4 v;
                v.x = f2bf(acc[m][n][0]);
                v.y = f2bf(acc[m][n][1]);
                v.z = f2bf(acc[m][n][2]);
                v.w = f2bf(acc[m][n][3]);
                *(ushort4*)&Out[((size_t)(bidx * 512 + col)) * 4096 + t0] = v;
            }
        }
    } else {
#pragma unroll
        for (int m = 0; m < 4; ++m) {
            const int rbase = row0 + wr * 64 + m * 16 + (lane >> 4) * 4;
#pragma unroll
            for (int n = 0; n < 4; ++n) {
                const int col = col0 + wc * 64 + n * 16 + (lane & 15);
#pragma unroll
                for (int j = 0; j < 4; ++j)
                    ((unsigned short*)OutP)[(size_t)(rbase + j) * 512 + col] =
                        f2bf(acc[m][n][j]);
            }
        }
    }
}

// ---------------------------------------------------------------------------
// gemm_big2: both 32768x512x512 GEMMs in one launch.
// z=0: G = Q @ M (f32 A fused cast, TRANSOUT)  z=1: Y = V @ N (row-major).
// grid (256, 4, 2), row index fastest (r11 mapping).
// ---------------------------------------------------------------------------
__global__ __launch_bounds__(256) void gemm_big2(const float* __restrict__ Q,
                                                 const unsigned short* __restrict__ Mt,
                                                 unsigned short* __restrict__ qTb,
                                                 const float* __restrict__ V,
                                                 const unsigned short* __restrict__ Nt,
                                                 unsigned short* __restrict__ Yb) {
    __shared__ __align__(16) unsigned short Asm[128 * 64];
    __shared__ __align__(16) unsigned short Bsm[128 * 64];
    const int z = blockIdx.z;
    const float* Ap          = z ? V : Q;
    const unsigned short* Bt = z ? Nt : Mt;
    void* Out                = z ? (void*)Yb : (void*)qTb;
    gemm_body<1>(Asm, Bsm, Ap, Bt, Out,
                 blockIdx.x * 128, blockIdx.y * 128, z == 0);
}

// both 512x512 mini-GEMMs in one launch; blockIdx.z selects the operand set
__global__ __launch_bounds__(256) void gemm_mini2(const unsigned short* __restrict__ A0,
                                                  const unsigned short* __restrict__ B0,
                                                  unsigned short* __restrict__ O0,
                                                  const unsigned short* __restrict__ A1,
                                                  const unsigned short* __restrict__ B1,
                                                  unsigned short* __restrict__ O1) {
    __shared__ __align__(16) unsigned short Asm[128 * 64];
    __shared__ __align__(16) unsigned short Bsm[128 * 64];
    const unsigned short* Ap = blockIdx.z ? A1 : A0;
    const unsigned short* Bt = blockIdx.z ? B1 : B0;
    unsigned short* Out      = blockIdx.z ? O1 : O0;
    gemm_body<0>(Asm, Bsm, Ap, Bt, Out, blockIdx.x * 128, blockIdx.y * 128, 0);
}

// ===========================================================================
// Register DFT-16 machinery (radix-4 DIF, compile-time twiddles in W64 units)
// ===========================================================================
constexpr double d_sin_t(double x) {
    double t = x, s = x; const double x2 = x * x;
    for (int i = 1; i < 10; ++i) { t *= -x2 / ((2.0 * i) * (2.0 * i + 1.0)); s += t; }
    return s;
}
constexpr double d_cos_t(double x) {
    double t = 1.0, s = 1.0; const double x2 = x * x;
    for (int i = 1; i < 10; ++i) { t *= -x2 / ((2.0 * i - 1.0) * (2.0 * i)); s += t; }
    return s;
}
struct TwTab {
    float c[64]; float s[64];
    constexpr TwTab() : c{}, s{} {
        for (int j = 0; j < 64; ++j) {
            const int q = j >> 4, r = j & 15;
            const double x = 6.283185307179586476925286766559 * r / 64.0;
            const double cc = d_cos_t(x), ss = d_sin_t(x);
            double cv, sv;
            if (q == 0)      { cv =  cc; sv =  ss; }
            else if (q == 1) { cv = -ss; sv =  cc; }
            else if (q == 2) { cv = -cc; sv = -ss; }
            else             { cv =  ss; sv = -cc; }
            c[j] = (float)cv; s[j] = (float)sv;
        }
    }
};
constexpr TwTab TW;

__device__ __host__ constexpr int perm16(int p) {    // reverse 2 base-4 digits
    return ((p & 3) << 2) | ((p >> 2) & 3);
}

template <int E, int SGN>
__device__ __forceinline__ void twmul(float& xr, float& xi) {
    if constexpr ((E & 63) != 0) {
        constexpr float wc = TW.c[E & 63];
        constexpr float ws = (SGN < 0) ? -TW.s[E & 63] : TW.s[E & 63];
        const float r  = xr * wc - xi * ws;
        const float i2 = xr * ws + xi * wc;
        xr = r; xi = i2;
    }
}

template <int E1, int E2, int E3, int SGN>
__device__ __forceinline__ void bf4(float& ar, float& ai, float& br, float& bi,
                                    float& cr, float& ci, float& er, float& ei) {
    const float t0r = ar + cr, t0i = ai + ci, t1r = ar - cr, t1i = ai - ci;
    const float t2r = br + er, t2i = bi + ei, t3r = br - er, t3i = bi - ei;
    ar = t0r + t2r; ai = t0i + t2i;
    float x2r = t0r - t2r, x2i = t0i - t2i;
    float x1r, x1i, x3r, x3i;
    if (SGN < 0) { x1r = t1r + t3i; x1i = t1i - t3r; x3r = t1r - t3i; x3i = t1i + t3r; }
    else         { x1r = t1r - t3i; x1i = t1i + t3r; x3r = t1r + t3i; x3i = t1i - t3r; }
    twmul<E1, SGN>(x1r, x1i);
    twmul<E2, SGN>(x2r, x2i);
    twmul<E3, SGN>(x3r, x3i);
    br = x1r; bi = x1i;
    cr = x2r; ci = x2i;
    er = x3r; ei = x3i;
}

template <int SGN, int... Is>
__device__ __forceinline__ void fft16_s0(float* dr, float* di, std::integer_sequence<int, Is...>) {
    (bf4<4 * Is, 8 * Is, 12 * Is, SGN>(dr[Is], di[Is], dr[Is + 4], di[Is + 4],
                                       dr[Is + 8], di[Is + 8], dr[Is + 12], di[Is + 12]), ...);
}
template <int SGN, int... Is>
__device__ __forceinline__ void fft16_s1(float* dr, float* di, std::integer_sequence<int, Is...>) {
    (bf4<0, 0, 0, SGN>(dr[4 * Is], di[4 * Is], dr[4 * Is + 1], di[4 * Is + 1],
                       dr[4 * Is + 2], di[4 * Is + 2], dr[4 * Is + 3], di[4 * Is + 3]), ...);
}
// input d[n] natural; output d[p] = X[perm16(p)]
template <int SGN>
__device__ __forceinline__ void fft16r(float* dr, float* di) {
    fft16_s0<SGN>(dr, di, std::make_integer_sequence<int, 4>{});
    fft16_s1<SGN>(dr, di, std::make_integer_sequence<int, 4>{});
}

// runtime twiddle by e^{SGN*2*pi*i*arev}  (arev in revolutions, exact fp32 int/2^k)
template <int SGN>
__device__ __forceinline__ void rtw(float& xr, float& xi, float arev) {
    const float f = arev - floorf(arev);
    const float s = __builtin_amdgcn_sinf(f);
    const float c = __builtin_amdgcn_cosf(f);
    float r, i2;
    if (SGN < 0) { r = xr * c + xi * s; i2 = xi * c - xr * s; }
    else         { r = xr * c - xi * s; i2 = xi * c + xr * s; }
    xr = r; xi = i2;
}

// complex mul by (c, -s): forward-FFT twiddle from table values
__device__ __forceinline__ void twmul_tab(float& xr, float& xi, float c, float s) {
    const float r  = xr * c + xi * s;
    const float i2 = xi * c - xr * s;
    xr = r; xi = i2;
}

// ---------------------------------------------------------------------------
// corr_fft16: 256 threads per 4096-pt FFT (16x16x16 Stockham), 16 elems/
// thread, CPBK=8 channels pipelined, Z^2 in registers, plain-store flush.
// Twiddles are CHANNEL-INVARIANT -> precomputed once per block into LDS
// (tw1: [15][256] stage-1, tw2: [15][16] stage-2a; identical values to the
// previous in-loop sincos -> bitwise identical results).
// LDS = 34 KB transpose + 32.6 KB tables = 66.6 KB (grid 512 = 2 blk/CU,
// grid-bound, so no occupancy loss). No launch-bounds hint (r13 lesson).
// z = g + i*krev_raw: sum_c (QWQ)_c x (KWK)_c = sum_e (QM)_e x K_e.
// Partial layout per block: SWIZZLED, natural freq k at
// a(k) = ((k&15)<<4)|((k>>4)&15)|(k&0xF00).  grid = NBLK = 512.
// ---------------------------------------------------------------------------
__global__ __launch_bounds__(256) void corr_fft16(const unsigned short* __restrict__ qT,
                                                  const unsigned short* __restrict__ kT,
                                                  float* __restrict__ Ppart) {
    __shared__ float tre[16 * TS];    // 17 KB
    __shared__ float tim[16 * TS];    // 17 KB
    __shared__ float tw1c[15 * 256], tw1s[15 * 256];   // 30 KB stage-1 twiddles
    __shared__ float tw2c[15 * 16],  tw2s[15 * 16];    // 1.9 KB stage-2a twiddles
    const int tid = threadIdx.x;
    const int b = blockIdx.x / (NBLK / B);
    const int local = blockIdx.x % (NBLK / B);
    const int hi = tid >> 4, lo = tid & 15;
    const int c0 = local * CPBK;

    // one-time twiddle tables (channel-invariant; same values as old rtw)
#pragma unroll
    for (int p = 1; p < 16; ++p) {
        const float a = (float)(tid * perm16(p)) * (1.0f / 4096.0f);
        const float f = a - floorf(a);
        tw1c[(p - 1) * 256 + tid] = __builtin_amdgcn_cosf(f);
        tw1s[(p - 1) * 256 + tid] = __builtin_amdgcn_sinf(f);
    }
    if (tid < 16) {
#pragma unroll
        for (int p = 1; p < 16; ++p) {
            const float a = (float)(tid * perm16(p)) * (1.0f / 256.0f);
            const float f = a - floorf(a);
            tw2c[(p - 1) * 16 + tid] = __builtin_amdgcn_cosf(f);
            tw2s[(p - 1) * 16 + tid] = __builtin_amdgcn_sinf(f);
        }
    }

    float dr[16], di[16], aR[16], aI[16];
    unsigned short puq[16], puk[16];
#pragma unroll
    for (int p = 0; p < 16; ++p) { aR[p] = 0.f; aI[p] = 0.f; }

    {   // prologue: load channel 0 directly
        const unsigned short* qrow = qT + ((size_t)(b * C + c0)) * L;
        const unsigned short* krow = kT + ((size_t)(b * C + c0)) * L;
#pragma unroll
        for (int n1 = 0; n1 < 16; ++n1) {
            dr[n1] = bf2f(qrow[n1 * 256 + tid]);
            di[n1] = bf2f(krow[(4096 - n1 * 256 - tid) & 4095]);
        }
    }
    __syncthreads();                         // twiddle tables ready

#pragma unroll 1
    for (int cc = 0; cc < CPBK; ++cc) {
        if (cc + 1 < CPBK) {   // issue next channel's loads (raw u16, convert later)
            const unsigned short* qrow = qT + ((size_t)(b * C + c0 + cc + 1)) * L;
            const unsigned short* krow = kT + ((size_t)(b * C + c0 + cc + 1)) * L;
#pragma unroll
            for (int n1 = 0; n1 < 16; ++n1) {
                puq[n1] = qrow[n1 * 256 + tid];
                puk[n1] = krow[(4096 - n1 * 256 - tid) & 4095];
            }
        }
        // stage 1: DFT16 over n1 (high digit), n = n1*256 + tid
        fft16r<-1>(dr, di);
#pragma unroll
        for (int p = 1; p < 16; ++p)
            twmul_tab(dr[p], di[p], tw1c[(p - 1) * 256 + tid], tw1s[(p - 1) * 256 + tid]);
        __syncthreads();                     // prev iteration's T2 reads done
#pragma unroll
        for (int p = 0; p < 16; ++p) {       // T1 write: y[k1][n2] @ k1*TS+m1*17+m2
            const int a = perm16(p) * TS + hi * 17 + lo;
            tre[a] = dr[p]; tim[a] = di[p];
        }
        __syncthreads();
#pragma unroll
        for (int q = 0; q < 16; ++q) {       // T1 read: thread (k1=hi, m2=lo), over m1
            const int a = hi * TS + q * 17 + lo;
            dr[q] = tre[a]; di[q] = tim[a];
        }
        fft16r<-1>(dr, di);                  // stage 2a: DFT16 over m1
#pragma unroll
        for (int p = 1; p < 16; ++p)
            twmul_tab(dr[p], di[p], tw2c[(p - 1) * 16 + lo], tw2s[(p - 1) * 16 + lo]);
        __syncthreads();
#pragma unroll
        for (int p = 0; p < 16; ++p) {       // T2 write: z[k1][k1'][m2]
            const int a = hi * TS + perm16(p) * 17 + lo;
            tre[a] = dr[p]; tim[a] = di[p];
        }
        __syncthreads();
#pragma unroll
        for (int q = 0; q < 16; ++q) {       // T2 read: thread (k1=hi, k1'=lo), over m2
            const int a = hi * TS + lo * 17 + q;
            dr[q] = tre[a]; di[q] = tim[a];
        }
        fft16r<-1>(dr, di);                  // stage 2b: DFT16 over m2
        // k = k1 + 16*k1' + 256*perm16(p); acc reg index p (channel-invariant)
#pragma unroll
        for (int p = 0; p < 16; ++p) {
            aR[p] += dr[p] * dr[p] - di[p] * di[p];
            aI[p] += 2.0f * dr[p] * di[p];
        }
        if (cc + 1 < CPBK) {   // rotate prefetched channel into working regs
#pragma unroll
            for (int n1 = 0; n1 < 16; ++n1) {
                dr[n1] = bf2f(puq[n1]);
                di[n1] = bf2f(puk[n1]);
            }
        }
    }

    // flush: plain float2 stores, coalesced across tid; per-block partial
    float* dst = Ppart + (size_t)blockIdx.x * (2 * NF);
#pragma unroll
    for (int p = 0; p < 16; ++p) {
        const int a = tid + (perm16(p) << 8);
        *(float2*)&dst[2 * a] = make_float2(aR[p], aI[p]);
    }
}

// ---------------------------------------------------------------------------
// reduce_pacc: Pacc[b][j] = sum_{g} Ppart[b*(NBLK/B)+g][j], j in [0, 2*NF)
// ---------------------------------------------------------------------------
__global__ __launch_bounds__(256) void reduce_pacc(const float* __restrict__ Ppart,
                                                   float* __restrict__ Pacc) {
    const int e = blockIdx.x * 256 + threadIdx.x;   // 0 .. 65535
    const int b = e >> 13;                          // 8192 floats per batch
    const int j = e & 8191;
    const float* src = Ppart + (size_t)b * (NBLK / B) * (2 * NF) + j;
    float s = 0.f;
#pragma unroll 4
    for (int g = 0; g < NBLK / B; ++g) s += src[(size_t)g * (2 * NF)];
    Pacc[e] = s;
}

// ---------------------------------------------------------------------------
// ifft_mean: same 16x16x16 structure, SGN=+1. Reads swizzled Pacc, writes
// mean_value[b][tau] natural. mean[tau] = Im(N*ifft(S))[tau] / (2*N*512).
// ---------------------------------------------------------------------------
__global__ __launch_bounds__(256) void ifft_mean(const float* __restrict__ Pacc,
                                                 float* __restrict__ mean_value) {
    __shared__ float tre[16 * TS];
    __shared__ float tim[16 * TS];
    const int tid = threadIdx.x;
    const int b = blockIdx.x;
    const int hi = tid >> 4, lo = tid & 15;
    const float* src = Pacc + (size_t)b * (2 * NF);

    float dr[16], di[16];
#pragma unroll
    for (int n1 = 0; n1 < 16; ++n1) {    // S[n1*256+tid] at swizzled a
        const int a = ((tid & 15) << 4) | (tid >> 4) | (n1 << 8);
        dr[n1] = src[2 * a]; di[n1] = src[2 * a + 1];
    }
    fft16r<1>(dr, di);
#pragma unroll
    for (int p = 1; p < 16; ++p)
        rtw<1>(dr[p], di[p], (float)(tid * perm16(p)) * (1.0f / 4096.0f));
#pragma unroll
    for (int p = 0; p < 16; ++p) {
        const int a = perm16(p) * TS + hi * 17 + lo;
        tre[a] = dr[p]; tim[a] = di[p];
    }
    __syncthreads();
#pragma unroll
    for (int q = 0; q < 16; ++q) {
        const int a = hi * TS + q * 17 + lo;
        dr[q] = tre[a]; di[q] = tim[a];
    }
    fft16r<1>(dr, di);
#pragma unroll
    for (int p = 1; p < 16; ++p)
        rtw<1>(dr[p], di[p], (float)(lo * perm16(p)) * (1.0f / 256.0f));
    __syncthreads();
#pragma unroll
    for (int p = 0; p < 16; ++p) {
        const int a = hi * TS + perm16(p) * 17 + lo;
        tre[a] = dr[p]; tim[a] = di[p];
    }
    __syncthreads();
#pragma unroll
    for (int q = 0; q < 16; ++q) {
        const int a = hi * TS + lo * 17 + q;
        dr[q] = tre[a]; di[q] = tim[a];
    }
    fft16r<1>(dr, di);

    const float scale = 1.0f / (2.0f * 4096.0f * 512.0f);
#pragma unroll
    for (int p = 0; p < 16; ++p) {
        const int k = hi + (lo << 4) + (perm16(p) << 8);
        mean_value[(size_t)b * NF + k] = di[p] * scale;
    }
}

// ---------------------------------------------------------------------------
__global__ __launch_bounds__(256) void topk_softmax(const float* __restrict__ mean_value,
                                                    int* __restrict__ idx_out,
                                                    float* __restrict__ tc_out) {
    __shared__ float mv[NF];
    __shared__ float rv[256];
    __shared__ int ri[256];
    __shared__ int sel[TOPK];
    const int tid = threadIdx.x;

    for (int j = 0; j < 16; ++j) {
        const int t = j * 256 + tid;
        float s = 0.f;
        for (int b = 0; b < B; ++b) s += mean_value[(size_t)b * NF + t];
        mv[t] = s * (1.0f / (float)B);
    }
    __syncthreads();

    for (int iter = 0; iter < TOPK; ++iter) {
        float bv = -INFINITY; int bi = NF;
        for (int j = 0; j < 16; ++j) {
            const int t = j * 256 + tid;
            const float v = mv[t];
            if (v > bv || (v == bv && t < bi)) { bv = v; bi = t; }
        }
        rv[tid] = bv; ri[tid] = bi;
        __syncthreads();
        for (int off = 128; off > 0; off >>= 1) {
            if (tid < off) {
                if (rv[tid + off] > rv[tid] ||
                    (rv[tid + off] == rv[tid] && ri[tid + off] < ri[tid])) {
                    rv[tid] = rv[tid + off]; ri[tid] = ri[tid + off];
                }
            }
            __syncthreads();
        }
        if (tid == 0) { sel[iter] = ri[0]; mv[ri[0]] = -INFINITY; }
        __syncthreads();
    }

    if (tid < B) {
        float wv[TOPK];
        float mx = -INFINITY;
        for (int i = 0; i < TOPK; ++i) {
            wv[i] = mean_value[(size_t)tid * NF + sel[i]];
            mx = fmaxf(mx, wv[i]);
        }
        float sum = 0.f;
        for (int i = 0; i < TOPK; ++i) { wv[i] = expf(wv[i] - mx); sum += wv[i]; }
        const float inv = 1.0f / sum;
        for (int i = 0; i < TOPK; ++i) tc_out[tid * TOPK + i] = wv[i] * inv;
    }
    if (tid < TOPK) idx_out[tid] = sel[tid];
}

// ---------------------------------------------------------------------------
// context_out: out[b,t,c] = sum_i tc[b][i] * Y[b,(t+idx[i])%L,c]
// Y bf16 (= V@(WV*Wfc)); out f32 (FINAL output — roll commutes with row-GEMM).
// ---------------------------------------------------------------------------
__global__ __launch_bounds__(256) void context_out(const unsigned short* __restrict__ Y,
                                                   const int* __restrict__ idx,
                                                   const float* __restrict__ tc,
                                                   float* __restrict__ out) {
    const size_t gid = (size_t)blockIdx.x * 256 + threadIdx.x;
    const int c8 = (int)(gid & 63);
    const int t  = (int)((gid >> 6) & 4095);
    const int b  = (int)(gid >> 18);

    __shared__ int sIdx[TOPK];
    __shared__ float sW[TOPK];
    if (threadIdx.x < TOPK) {
        sIdx[threadIdx.x] = idx[threadIdx.x];
        sW[threadIdx.x]   = tc[b * TOPK + threadIdx.x];
    }
    __syncthreads();

    const unsigned short* yb = Y + (size_t)b * L * C;
    float a[8] = {};
#pragma unroll
    for (int i = 0; i < TOPK; ++i) {
        const int row = (t + sIdx[i]) & (L - 1);
        const uint4 v = *(const uint4*)&yb[(size_t)row * C + c8 * 8];
        const float wgt = sW[i];
        a[0] += wgt * bf2f((unsigned short)(v.x & 0xFFFF));
        a[1] += wgt * bf2f((unsigned short)(v.x >> 16));
        a[2] += wgt * bf2f((unsigned short)(v.y & 0xFFFF));
        a[3] += wgt * bf2f((unsigned short)(v.y >> 16));
        a[4] += wgt * bf2f((unsigned short)(v.z & 0xFFFF));
        a[5] += wgt * bf2f((unsigned short)(v.z >> 16));
        a[6] += wgt * bf2f((unsigned short)(v.w & 0xFFFF));
        a[7] += wgt * bf2f((unsigned short)(v.w >> 16));
    }
    float* o = out + gid * 8;
    *(float4*)&o[0] = make_float4(a[0], a[1], a[2], a[3]);
    *(float4*)&o[4] = make_float4(a[4], a[5], a[6], a[7]);
}

// ---------------------------------------------------------------------------
extern "C" void kernel_launch(void* const* d_in, const int* in_sizes, int n_in,
                              void* d_out, int out_size, void* d_ws, size_t ws_size,
                              hipStream_t stream) {
    const float* Q   = (const float*)d_in[0];
    const float* K   = (const float*)d_in[1];
    const float* V   = (const float*)d_in[2];
    const float* WQ  = (const float*)d_in[4];
    const float* WK  = (const float*)d_in[5];
    const float* WV  = (const float*)d_in[6];
    const float* Wfc = (const float*)d_in[7];
    float* out = (float*)d_out;

    const size_t SZ = (size_t)B * L * C;          // 16,777,216 elements
    const size_t WSZ = 512 * 512;
    unsigned short* kTb  = (unsigned short*)d_ws; // 32 MB (B,C,L) raw-K bf16
    unsigned short* qTb  = kTb + SZ;              // 32 MB (B,C,L) G = Q@M
    unsigned short* Yb   = qTb + SZ;              // 32 MB (B,L,C) Y = V@(WV*Wfc)
    unsigned short* WQb  = Yb + SZ;               // 512 KB each
    unsigned short* WKb  = WQb + WSZ;
    unsigned short* WVb  = WKb + WSZ;
    unsigned short* Wfct = WVb + WSZ;             // Wfc^T (N x K)
    unsigned short* Mt   = Wfct + WSZ;            // Mt[e][d] = (WK WQ^T)[e,d]
    unsigned short* Nt   = Mt + WSZ;              // Nt[f][d] = (WV Wfc)[d,f]
    float* Ppart      = (float*)(Nt + WSZ);           // NBLK * 2*NF = 16 MB
    float* Pacc       = Ppart + (size_t)NBLK * 2 * NF; // B*2*NF (swizzled)
    float* mean_value = Pacc + (size_t)B * 2 * NF;    // B*NF
    float* tc         = mean_value + (size_t)B * NF;  // B*TOPK
    int*   idx        = (int*)(tc + B * TOPK);        // TOPK

    cvt_bf16_3<<<dim3(128, 1, 3), 256, 0, stream>>>(
        (const float4*)WQ, (uint4*)WQb,
        (const float4*)WK, (uint4*)WKb,
        (const float4*)WV, (uint4*)WVb);
    wtrans<<<dim3(16, 16), 256, 0, stream>>>(Wfc, Wfct);
    ktrans<<<dim3(64, 8, 8), 256, 0, stream>>>(K, kTb);

    // z=0: Mt[e][d] = sum_c WK[e,c]*WQ[d,c]
    // z=1: Nt[f][d] = sum_c Wfct[f,c]*WVb[d,c] = (WV@Wfc)[d,f]
    gemm_mini2<<<dim3(4, 4, 2), 256, 0, stream>>>(WKb, WQb, Mt, Wfct, WVb, Nt);
    // z=0: G = Q@M (TRANSOUT)   z=1: Y = V@N (row-major) — one launch
    gemm_big2<<<dim3(256, 4, 2), 256, 0, stream>>>(Q, Mt, qTb, V, Nt, Yb);

    corr_fft16<<<dim3(NBLK), 256, 0, stream>>>(qTb, kTb, Ppart);
    reduce_pacc<<<dim3(256), 256, 0, stream>>>(Ppart, Pacc);
    ifft_mean<<<dim3(B), 256, 0, stream>>>(Pacc, mean_value);
    topk_softmax<<<dim3(1), 256, 0, stream>>>(mean_value, idx, tc);

    context_out<<<dim3(8192), 256, 0, stream>>>(Yb, idx, tc, out);
}

// Round 20
// 228.715 us; speedup vs baseline: 1.2733x; 1.0273x over previous
//
#include <hip/hip_runtime.h>
#include <math.h>
#include <utility>

#define B 8
#define L 4096
#define C 512          // H*DK == H*DV == 512
#define NF 4096        // FFT length == L
#define TOPK 8
#define TS 272         // padded LDS row stride (16*17)
#define CPBK 8         // channels per block in corr_fft16
#define NBLK (B * C / CPBK)   // 512 corr blocks

typedef short bf16x8 __attribute__((ext_vector_type(8)));
typedef float f32x4 __attribute__((ext_vector_type(4)));

__device__ inline unsigned short f2bf(float f) {
    unsigned int u = __float_as_uint(f);
    u += 0x7FFF + ((u >> 16) & 1);          // round-to-nearest-even
    return (unsigned short)(u >> 16);
}
__device__ inline float bf2f(unsigned short h) {
    return __uint_as_float(((unsigned int)h) << 16);
}

__device__ inline void gload_lds16(const void* g, void* l) {
    __builtin_amdgcn_global_load_lds(
        (const __attribute__((address_space(1))) void*)g,
        (__attribute__((address_space(3))) void*)l, 16, 0, 0);
}

// ---------------------------------------------------------------------------
// f32 -> bf16 for the 3 square weights in one launch (z selects tensor)
// ---------------------------------------------------------------------------
__global__ __launch_bounds__(256) void cvt_bf16_3(const float4* __restrict__ i0,
                                                  uint4* __restrict__ o0,
                                                  const float4* __restrict__ i1,
                                                  uint4* __restrict__ o1,
                                                  const float4* __restrict__ i2,
                                                  uint4* __restrict__ o2) {
    const float4* in = blockIdx.z == 0 ? i0 : (blockIdx.z == 1 ? i1 : i2);
    uint4* out       = blockIdx.z == 0 ? o0 : (blockIdx.z == 1 ? o1 : o2);
    const int gid = blockIdx.x * 256 + threadIdx.x;
    const float4 a = in[gid * 2];
    const float4 b = in[gid * 2 + 1];
    uint4 o;
    o.x = (unsigned)f2bf(a.x) | ((unsigned)f2bf(a.y) << 16);
    o.y = (unsigned)f2bf(a.z) | ((unsigned)f2bf(a.w) << 16);
    o.z = (unsigned)f2bf(b.x) | ((unsigned)f2bf(b.y) << 16);
    o.w = (unsigned)f2bf(b.z) | ((unsigned)f2bf(b.w) << 16);
    out[gid] = o;
}

// ---------------------------------------------------------------------------
// K (B,L,512 f32) -> kTb (B,512,L bf16) transpose; 64x64 tiles, 256 thr.
// ---------------------------------------------------------------------------
__global__ __launch_bounds__(256) void ktrans(const float* __restrict__ Kin,
                                              unsigned short* __restrict__ kTb) {
    __shared__ float tile[64][65];
    const int t0 = blockIdx.x * 64;
    const int c0 = blockIdx.y * 64;
    const int b  = blockIdx.z;
    const int tid = threadIdx.x;
    const int tc = tid & 63, tr = tid >> 6;
#pragma unroll
    for (int i = 0; i < 16; ++i) {
        const int r = tr + i * 4;
        tile[r][tc] = Kin[((size_t)(b * 4096) + t0 + r) * 512 + c0 + tc];
    }
    __syncthreads();
#pragma unroll
    for (int i = 0; i < 16; ++i) {
        const int cc = tr + i * 4;
        kTb[((size_t)(b * 512) + c0 + cc) * 4096 + t0 + tc] = f2bf(tile[tc][cc]);
    }
}

// ---------------------------------------------------------------------------
// W (512x512 f32, K x N) -> Wt (N x K, bf16), 32x32 LDS tiles
// ---------------------------------------------------------------------------
__global__ __launch_bounds__(256) void wtrans(const float* __restrict__ W,
                                              unsigned short* __restrict__ Wt) {
    __shared__ float t[32][33];
    const int tx = threadIdx.x & 31, ty = threadIdx.x >> 5;   // 32 x 8
    const int bx = blockIdx.x;   // N tile
    const int by = blockIdx.y;   // K tile
#pragma unroll
    for (int i = 0; i < 4; ++i) {
        const int k = by * 32 + ty + i * 8;
        t[ty + i * 8][tx] = W[(size_t)k * 512 + bx * 32 + tx];   // t[k][n]
    }
    __syncthreads();
#pragma unroll
    for (int i = 0; i < 4; ++i) {
        const int n = bx * 32 + ty + i * 8;
        Wt[(size_t)n * 512 + by * 32 + tx] = f2bf(t[tx][ty + i * 8]);
    }
}

// ---------------------------------------------------------------------------
// Shared GEMM tile body: C[128x128] at (row0, col0) = A * Bt^T over K=512.
// F32A=1: A f32, cast fused into reg-staged A; sub-tiles 0-1 are T14
// software-prefetched (loads for k+1 issued during MFMA of k -> A latency
// hidden; only +16 VGPR so occupancy stays at 4 waves/SIMD).
// transout (runtime, block-uniform): 1 -> bf16 out at [(b*512+col)*4096+t]
// (b = row0>>12); 0 -> row-major bf16. Hot loop identical either way.
// ---------------------------------------------------------------------------
template <int F32A>
__device__ __forceinline__ void gemm_body(unsigned short* Asm, unsigned short* Bsm,
                                          const void* __restrict__ Ap,
                                          const unsigned short* __restrict__ Bt,
                                          void* __restrict__ OutP,
                                          int row0, int col0, int transout) {
    const int tid = threadIdx.x;
    const int lane = tid & 63;
    const int w = tid >> 6;
    const int wr = w >> 1, wc = w & 1;

    const int ldr = tid >> 3;            // 0..31: row within 32-row group
    const int ldk = (tid & 7) << 3;      // k offset (8 elems per lane)
    const int ldsbase = (w << 3) * 64;   // wave's 8-row base within group

    f32x4 acc[4][4] = {};
    float4 pvA[2], pvB[2];               // T14 prefetch regs, sub-tiles 0,1

    if (F32A) {
        const float* Af = (const float*)Ap;
#pragma unroll
        for (int i = 0; i < 2; ++i) {
            const size_t base = (size_t)(row0 + i * 32 + ldr) * 512 + ldk;
            (i == 0 ? pvA[0] : pvB[0]) = *(const float4*)&Af[base];
            (i == 0 ? pvA[1] : pvB[1]) = *(const float4*)&Af[base + 4];
        }
    }

    for (int k0 = 0; k0 < 512; k0 += 64) {
        __syncthreads();
#pragma unroll
        for (int i = 0; i < 4; ++i) {
            if (F32A) {
                const float* Af = (const float*)Ap;
                float4 v0, v1;
                if (i == 0)      { v0 = pvA[0]; v1 = pvA[1]; }
                else if (i == 1) { v0 = pvB[0]; v1 = pvB[1]; }
                else {
                    const size_t base = (size_t)(row0 + i * 32 + ldr) * 512 + k0 + ldk;
                    v0 = *(const float4*)&Af[base];
                    v1 = *(const float4*)&Af[base + 4];
                }
                ushort4 u0, u1;
                u0.x = f2bf(v0.x); u0.y = f2bf(v0.y); u0.z = f2bf(v0.z); u0.w = f2bf(v0.w);
                u1.x = f2bf(v1.x); u1.y = f2bf(v1.y); u1.z = f2bf(v1.z); u1.w = f2bf(v1.w);
                *(ushort4*)&Asm[i * 2048 + ldr * 64 + ldk]     = u0;
                *(ushort4*)&Asm[i * 2048 + ldr * 64 + ldk + 4] = u1;
            } else {
                gload_lds16((const unsigned short*)Ap +
                                (size_t)(row0 + i * 32 + ldr) * 512 + k0 + ldk,
                            Asm + i * 32 * 64 + ldsbase);
            }
            gload_lds16(Bt + (size_t)(col0 + i * 32 + ldr) * 512 + k0 + ldk,
                        Bsm + i * 32 * 64 + ldsbase);
        }
        __syncthreads();

        if (F32A && k0 + 64 < 512) {     // T14: issue next-k A loads under MFMA
            const float* Af = (const float*)Ap;
            {
                const size_t base = (size_t)(row0 + 0 * 32 + ldr) * 512 + (k0 + 64) + ldk;
                pvA[0] = *(const float4*)&Af[base];
                pvA[1] = *(const float4*)&Af[base + 4];
            }
            {
                const size_t base = (size_t)(row0 + 1 * 32 + ldr) * 512 + (k0 + 64) + ldk;
                pvB[0] = *(const float4*)&Af[base];
                pvB[1] = *(const float4*)&Af[base + 4];
            }
        }
#pragma unroll
        for (int kk = 0; kk < 2; ++kk) {
            bf16x8 af[4], bfv[4];
#pragma unroll
            for (int m = 0; m < 4; ++m)
                af[m] = *(const bf16x8*)&Asm[(wr * 64 + m * 16 + (lane & 15)) * 64 +
                                             kk * 32 + (lane >> 4) * 8];
#pragma unroll
            for (int n = 0; n < 4; ++n)
                bfv[n] = *(const bf16x8*)&Bsm[(wc * 64 + n * 16 + (lane & 15)) * 64 +
                                              kk * 32 + (lane >> 4) * 8];
#pragma unroll
            for (int m = 0; m < 4; ++m)
#pragma unroll
                for (int n = 0; n < 4; ++n)
                    acc[m][n] = __builtin_amdgcn_mfma_f32_16x16x32_bf16(
                        af[m], bfv[n], acc[m][n], 0, 0, 0);
        }
    }

    if (transout) {
        unsigned short* Out = (unsigned short*)OutP;
        const int bidx = row0 >> 12;
        const int t0base = (row0 & 4095) + wr * 64 + (lane >> 4) * 4;
#pragma unroll
        for (int n = 0; n < 4; ++n) {
            const int col = col0 + wc * 64 + n * 16 + (lane & 15);
#pragma unroll
            for (int m = 0; m < 4; ++m) {
                const int t0 = t0base + m * 16;
                ushort4 v;
                v.x = f2bf(acc[m][n][0]);
                v.y = f2bf(acc[m][n][1]);
                v.z = f2bf(acc[m][n][2]);
                v.w = f2bf(acc[m][n][3]);
                *(ushort4*)&Out[((size_t)(bidx * 512 + col)) * 4096 + t0] = v;
            }
        }
    } else {
#pragma unroll
        for (int m = 0; m < 4; ++m) {
            const int rbase = row0 + wr * 64 + m * 16 + (lane >> 4) * 4;
#pragma unroll
            for (int n = 0; n < 4; ++n) {
                const int col = col0 + wc * 64 + n * 16 + (lane & 15);
#pragma unroll
                for (int j = 0; j < 4; ++j)
                    ((unsigned short*)OutP)[(size_t)(rbase + j) * 512 + col] =
                        f2bf(acc[m][n][j]);
            }
        }
    }
}

// ---------------------------------------------------------------------------
// gemm_big2: both 32768x512x512 GEMMs in one launch.
// z=0: G = Q @ M (f32 A fused cast, TRANSOUT)  z=1: Y = V @ N (row-major).
// grid (256, 4, 2), row index fastest (r11 mapping).
// ---------------------------------------------------------------------------
__global__ __launch_bounds__(256) void gemm_big2(const float* __restrict__ Q,
                                                 const unsigned short* __restrict__ Mt,
                                                 unsigned short* __restrict__ qTb,
                                                 const float* __restrict__ V,
                                                 const unsigned short* __restrict__ Nt,
                                                 unsigned short* __restrict__ Yb) {
    __shared__ __align__(16) unsigned short Asm[128 * 64];
    __shared__ __align__(16) unsigned short Bsm[128 * 64];
    const int z = blockIdx.z;
    const float* Ap          = z ? V : Q;
    const unsigned short* Bt = z ? Nt : Mt;
    void* Out                = z ? (void*)Yb : (void*)qTb;
    gemm_body<1>(Asm, Bsm, Ap, Bt, Out,
                 blockIdx.x * 128, blockIdx.y * 128, z == 0);
}

// both 512x512 mini-GEMMs in one launch; blockIdx.z selects the operand set
__global__ __launch_bounds__(256) void gemm_mini2(const unsigned short* __restrict__ A0,
                                                  const unsigned short* __restrict__ B0,
                                                  unsigned short* __restrict__ O0,
                                                  const unsigned short* __restrict__ A1,
                                                  const unsigned short* __restrict__ B1,
                                                  unsigned short* __restrict__ O1) {
    __shared__ __align__(16) unsigned short Asm[128 * 64];
    __shared__ __align__(16) unsigned short Bsm[128 * 64];
    const unsigned short* Ap = blockIdx.z ? A1 : A0;
    const unsigned short* Bt = blockIdx.z ? B1 : B0;
    unsigned short* Out      = blockIdx.z ? O1 : O0;
    gemm_body<0>(Asm, Bsm, Ap, Bt, Out, blockIdx.x * 128, blockIdx.y * 128, 0);
}

// ===========================================================================
// Register DFT-16 machinery (radix-4 DIF, compile-time twiddles in W64 units)
// ===========================================================================
constexpr double d_sin_t(double x) {
    double t = x, s = x; const double x2 = x * x;
    for (int i = 1; i < 10; ++i) { t *= -x2 / ((2.0 * i) * (2.0 * i + 1.0)); s += t; }
    return s;
}
constexpr double d_cos_t(double x) {
    double t = 1.0, s = 1.0; const double x2 = x * x;
    for (int i = 1; i < 10; ++i) { t *= -x2 / ((2.0 * i - 1.0) * (2.0 * i)); s += t; }
    return s;
}
struct TwTab {
    float c[64]; float s[64];
    constexpr TwTab() : c{}, s{} {
        for (int j = 0; j < 64; ++j) {
            const int q = j >> 4, r = j & 15;
            const double x = 6.283185307179586476925286766559 * r / 64.0;
            const double cc = d_cos_t(x), ss = d_sin_t(x);
            double cv, sv;
            if (q == 0)      { cv =  cc; sv =  ss; }
            else if (q == 1) { cv = -ss; sv =  cc; }
            else if (q == 2) { cv = -cc; sv = -ss; }
            else             { cv =  ss; sv = -cc; }
            c[j] = (float)cv; s[j] = (float)sv;
        }
    }
};
constexpr TwTab TW;

__device__ __host__ constexpr int perm16(int p) {    // reverse 2 base-4 digits
    return ((p & 3) << 2) | ((p >> 2) & 3);
}

template <int E, int SGN>
__device__ __forceinline__ void twmul(float& xr, float& xi) {
    if constexpr ((E & 63) != 0) {
        constexpr float wc = TW.c[E & 63];
        constexpr float ws = (SGN < 0) ? -TW.s[E & 63] : TW.s[E & 63];
        const float r  = xr * wc - xi * ws;
        const float i2 = xr * ws + xi * wc;
        xr = r; xi = i2;
    }
}

template <int E1, int E2, int E3, int SGN>
__device__ __forceinline__ void bf4(float& ar, float& ai, float& br, float& bi,
                                    float& cr, float& ci, float& er, float& ei) {
    const float t0r = ar + cr, t0i = ai + ci, t1r = ar - cr, t1i = ai - ci;
    const float t2r = br + er, t2i = bi + ei, t3r = br - er, t3i = bi - ei;
    ar = t0r + t2r; ai = t0i + t2i;
    float x2r = t0r - t2r, x2i = t0i - t2i;
    float x1r, x1i, x3r, x3i;
    if (SGN < 0) { x1r = t1r + t3i; x1i = t1i - t3r; x3r = t1r - t3i; x3i = t1i + t3r; }
    else         { x1r = t1r - t3i; x1i = t1i + t3r; x3r = t1r + t3i; x3i = t1i - t3r; }
    twmul<E1, SGN>(x1r, x1i);
    twmul<E2, SGN>(x2r, x2i);
    twmul<E3, SGN>(x3r, x3i);
    br = x1r; bi = x1i;
    cr = x2r; ci = x2i;
    er = x3r; ei = x3i;
}

template <int SGN, int... Is>
__device__ __forceinline__ void fft16_s0(float* dr, float* di, std::integer_sequence<int, Is...>) {
    (bf4<4 * Is, 8 * Is, 12 * Is, SGN>(dr[Is], di[Is], dr[Is + 4], di[Is + 4],
                                       dr[Is + 8], di[Is + 8], dr[Is + 12], di[Is + 12]), ...);
}
template <int SGN, int... Is>
__device__ __forceinline__ void fft16_s1(float* dr, float* di, std::integer_sequence<int, Is...>) {
    (bf4<0, 0, 0, SGN>(dr[4 * Is], di[4 * Is], dr[4 * Is + 1], di[4 * Is + 1],
                       dr[4 * Is + 2], di[4 * Is + 2], dr[4 * Is + 3], di[4 * Is + 3]), ...);
}
// input d[n] natural; output d[p] = X[perm16(p)]
template <int SGN>
__device__ __forceinline__ void fft16r(float* dr, float* di) {
    fft16_s0<SGN>(dr, di, std::make_integer_sequence<int, 4>{});
    fft16_s1<SGN>(dr, di, std::make_integer_sequence<int, 4>{});
}

// runtime twiddle by e^{SGN*2*pi*i*arev}  (arev in revolutions, exact fp32 int/2^k)
template <int SGN>
__device__ __forceinline__ void rtw(float& xr, float& xi, float arev) {
    const float f = arev - floorf(arev);
    const float s = __builtin_amdgcn_sinf(f);
    const float c = __builtin_amdgcn_cosf(f);
    float r, i2;
    if (SGN < 0) { r = xr * c + xi * s; i2 = xi * c - xr * s; }
    else         { r = xr * c - xi * s; i2 = xi * c + xr * s; }
    xr = r; xi = i2;
}

// complex mul by (c, -s): forward-FFT twiddle from table values
__device__ __forceinline__ void twmul_tab(float& xr, float& xi, float c, float s) {
    const float r  = xr * c + xi * s;
    const float i2 = xi * c - xr * s;
    xr = r; xi = i2;
}

// ---------------------------------------------------------------------------
// corr_fft16: 256 threads per 4096-pt FFT (16x16x16 Stockham), 16 elems/
// thread, CPBK=8 channels pipelined, Z^2 in registers, plain-store flush.
// Channel-invariant twiddles precomputed once per block into LDS (r19 win).
// LDS = 34 KB transpose + 32.6 KB tables. grid = NBLK = 512.
// z = g + i*krev_raw: sum_c (QWQ)_c x (KWK)_c = sum_e (QM)_e x K_e.
// Partial layout per block: SWIZZLED, natural freq k at
// a(k) = ((k&15)<<4)|((k>>4)&15)|(k&0xF00).
// ---------------------------------------------------------------------------
__global__ __launch_bounds__(256) void corr_fft16(const unsigned short* __restrict__ qT,
                                                  const unsigned short* __restrict__ kT,
                                                  float* __restrict__ Ppart) {
    __shared__ float tre[16 * TS];    // 17 KB
    __shared__ float tim[16 * TS];    // 17 KB
    __shared__ float tw1c[15 * 256], tw1s[15 * 256];   // 30 KB stage-1 twiddles
    __shared__ float tw2c[15 * 16],  tw2s[15 * 16];    // 1.9 KB stage-2a twiddles
    const int tid = threadIdx.x;
    const int b = blockIdx.x / (NBLK / B);
    const int local = blockIdx.x % (NBLK / B);
    const int hi = tid >> 4, lo = tid & 15;
    const int c0 = local * CPBK;

    // one-time twiddle tables (channel-invariant; same values as old rtw)
#pragma unroll
    for (int p = 1; p < 16; ++p) {
        const float a = (float)(tid * perm16(p)) * (1.0f / 4096.0f);
        const float f = a - floorf(a);
        tw1c[(p - 1) * 256 + tid] = __builtin_amdgcn_cosf(f);
        tw1s[(p - 1) * 256 + tid] = __builtin_amdgcn_sinf(f);
    }
    if (tid < 16) {
#pragma unroll
        for (int p = 1; p < 16; ++p) {
            const float a = (float)(tid * perm16(p)) * (1.0f / 256.0f);
            const float f = a - floorf(a);
            tw2c[(p - 1) * 16 + tid] = __builtin_amdgcn_cosf(f);
            tw2s[(p - 1) * 16 + tid] = __builtin_amdgcn_sinf(f);
        }
    }

    float dr[16], di[16], aR[16], aI[16];
    unsigned short puq[16], puk[16];
#pragma unroll
    for (int p = 0; p < 16; ++p) { aR[p] = 0.f; aI[p] = 0.f; }

    {   // prologue: load channel 0 directly
        const unsigned short* qrow = qT + ((size_t)(b * C + c0)) * L;
        const unsigned short* krow = kT + ((size_t)(b * C + c0)) * L;
#pragma unroll
        for (int n1 = 0; n1 < 16; ++n1) {
            dr[n1] = bf2f(qrow[n1 * 256 + tid]);
            di[n1] = bf2f(krow[(4096 - n1 * 256 - tid) & 4095]);
        }
    }
    __syncthreads();                         // twiddle tables ready

#pragma unroll 1
    for (int cc = 0; cc < CPBK; ++cc) {
        if (cc + 1 < CPBK) {   // issue next channel's loads (raw u16, convert later)
            const unsigned short* qrow = qT + ((size_t)(b * C + c0 + cc + 1)) * L;
            const unsigned short* krow = kT + ((size_t)(b * C + c0 + cc + 1)) * L;
#pragma unroll
            for (int n1 = 0; n1 < 16; ++n1) {
                puq[n1] = qrow[n1 * 256 + tid];
                puk[n1] = krow[(4096 - n1 * 256 - tid) & 4095];
            }
        }
        // stage 1: DFT16 over n1 (high digit), n = n1*256 + tid
        fft16r<-1>(dr, di);
#pragma unroll
        for (int p = 1; p < 16; ++p)
            twmul_tab(dr[p], di[p], tw1c[(p - 1) * 256 + tid], tw1s[(p - 1) * 256 + tid]);
        __syncthreads();                     // prev iteration's T2 reads done
#pragma unroll
        for (int p = 0; p < 16; ++p) {       // T1 write: y[k1][n2] @ k1*TS+m1*17+m2
            const int a = perm16(p) * TS + hi * 17 + lo;
            tre[a] = dr[p]; tim[a] = di[p];
        }
        __syncthreads();
#pragma unroll
        for (int q = 0; q < 16; ++q) {       // T1 read: thread (k1=hi, m2=lo), over m1
            const int a = hi * TS + q * 17 + lo;
            dr[q] = tre[a]; di[q] = tim[a];
        }
        fft16r<-1>(dr, di);                  // stage 2a: DFT16 over m1
#pragma unroll
        for (int p = 1; p < 16; ++p)
            twmul_tab(dr[p], di[p], tw2c[(p - 1) * 16 + lo], tw2s[(p - 1) * 16 + lo]);
        __syncthreads();
#pragma unroll
        for (int p = 0; p < 16; ++p) {       // T2 write: z[k1][k1'][m2]
            const int a = hi * TS + perm16(p) * 17 + lo;
            tre[a] = dr[p]; tim[a] = di[p];
        }
        __syncthreads();
#pragma unroll
        for (int q = 0; q < 16; ++q) {       // T2 read: thread (k1=hi, k1'=lo), over m2
            const int a = hi * TS + lo * 17 + q;
            dr[q] = tre[a]; di[q] = tim[a];
        }
        fft16r<-1>(dr, di);                  // stage 2b: DFT16 over m2
        // k = k1 + 16*k1' + 256*perm16(p); acc reg index p (channel-invariant)
#pragma unroll
        for (int p = 0; p < 16; ++p) {
            aR[p] += dr[p] * dr[p] - di[p] * di[p];
            aI[p] += 2.0f * dr[p] * di[p];
        }
        if (cc + 1 < CPBK) {   // rotate prefetched channel into working regs
#pragma unroll
            for (int n1 = 0; n1 < 16; ++n1) {
                dr[n1] = bf2f(puq[n1]);
                di[n1] = bf2f(puk[n1]);
            }
        }
    }

    // flush: plain float2 stores, coalesced across tid; per-block partial
    float* dst = Ppart + (size_t)blockIdx.x * (2 * NF);
#pragma unroll
    for (int p = 0; p < 16; ++p) {
        const int a = tid + (perm16(p) << 8);
        *(float2*)&dst[2 * a] = make_float2(aR[p], aI[p]);
    }
}

// ---------------------------------------------------------------------------
// reduce_pacc: Pacc[b][j] = sum_{g} Ppart[b*(NBLK/B)+g][j], j in [0, 2*NF)
// ---------------------------------------------------------------------------
__global__ __launch_bounds__(256) void reduce_pacc(const float* __restrict__ Ppart,
                                                   float* __restrict__ Pacc) {
    const int e = blockIdx.x * 256 + threadIdx.x;   // 0 .. 65535
    const int b = e >> 13;                          // 8192 floats per batch
    const int j = e & 8191;
    const float* src = Ppart + (size_t)b * (NBLK / B) * (2 * NF) + j;
    float s = 0.f;
#pragma unroll 4
    for (int g = 0; g < NBLK / B; ++g) s += src[(size_t)g * (2 * NF)];
    Pacc[e] = s;
}

// ---------------------------------------------------------------------------
// ifft_mean: same 16x16x16 structure, SGN=+1. Reads swizzled Pacc, writes
// mean_value[b][tau] natural. mean[tau] = Im(N*ifft(S))[tau] / (2*N*512).
// ---------------------------------------------------------------------------
__global__ __launch_bounds__(256) void ifft_mean(const float* __restrict__ Pacc,
                                                 float* __restrict__ mean_value) {
    __shared__ float tre[16 * TS];
    __shared__ float tim[16 * TS];
    const int tid = threadIdx.x;
    const int b = blockIdx.x;
    const int hi = tid >> 4, lo = tid & 15;
    const float* src = Pacc + (size_t)b * (2 * NF);

    float dr[16], di[16];
#pragma unroll
    for (int n1 = 0; n1 < 16; ++n1) {    // S[n1*256+tid] at swizzled a
        const int a = ((tid & 15) << 4) | (tid >> 4) | (n1 << 8);
        dr[n1] = src[2 * a]; di[n1] = src[2 * a + 1];
    }
    fft16r<1>(dr, di);
#pragma unroll
    for (int p = 1; p < 16; ++p)
        rtw<1>(dr[p], di[p], (float)(tid * perm16(p)) * (1.0f / 4096.0f));
#pragma unroll
    for (int p = 0; p < 16; ++p) {
        const int a = perm16(p) * TS + hi * 17 + lo;
        tre[a] = dr[p]; tim[a] = di[p];
    }
    __syncthreads();
#pragma unroll
    for (int q = 0; q < 16; ++q) {
        const int a = hi * TS + q * 17 + lo;
        dr[q] = tre[a]; di[q] = tim[a];
    }
    fft16r<1>(dr, di);
#pragma unroll
    for (int p = 1; p < 16; ++p)
        rtw<1>(dr[p], di[p], (float)(lo * perm16(p)) * (1.0f / 256.0f));
    __syncthreads();
#pragma unroll
    for (int p = 0; p < 16; ++p) {
        const int a = hi * TS + perm16(p) * 17 + lo;
        tre[a] = dr[p]; tim[a] = di[p];
    }
    __syncthreads();
#pragma unroll
    for (int q = 0; q < 16; ++q) {
        const int a = hi * TS + lo * 17 + q;
        dr[q] = tre[a]; di[q] = tim[a];
    }
    fft16r<1>(dr, di);

    const float scale = 1.0f / (2.0f * 4096.0f * 512.0f);
#pragma unroll
    for (int p = 0; p < 16; ++p) {
        const int k = hi + (lo << 4) + (perm16(p) << 8);
        mean_value[(size_t)b * NF + k] = di[p] * scale;
    }
}

// ---------------------------------------------------------------------------
__global__ __launch_bounds__(256) void topk_softmax(const float* __restrict__ mean_value,
                                                    int* __restrict__ idx_out,
                                                    float* __restrict__ tc_out) {
    __shared__ float mv[NF];
    __shared__ float rv[256];
    __shared__ int ri[256];
    __shared__ int sel[TOPK];
    const int tid = threadIdx.x;

    for (int j = 0; j < 16; ++j) {
        const int t = j * 256 + tid;
        float s = 0.f;
        for (int b = 0; b < B; ++b) s += mean_value[(size_t)b * NF + t];
        mv[t] = s * (1.0f / (float)B);
    }
    __syncthreads();

    for (int iter = 0; iter < TOPK; ++iter) {
        float bv = -INFINITY; int bi = NF;
        for (int j = 0; j < 16; ++j) {
            const int t = j * 256 + tid;
            const float v = mv[t];
            if (v > bv || (v == bv && t < bi)) { bv = v; bi = t; }
        }
        rv[tid] = bv; ri[tid] = bi;
        __syncthreads();
        for (int off = 128; off > 0; off >>= 1) {
            if (tid < off) {
                if (rv[tid + off] > rv[tid] ||
                    (rv[tid + off] == rv[tid] && ri[tid + off] < ri[tid])) {
                    rv[tid] = rv[tid + off]; ri[tid] = ri[tid + off];
                }
            }
            __syncthreads();
        }
        if (tid == 0) { sel[iter] = ri[0]; mv[ri[0]] = -INFINITY; }
        __syncthreads();
    }

    if (tid < B) {
        float wv[TOPK];
        float mx = -INFINITY;
        for (int i = 0; i < TOPK; ++i) {
            wv[i] = mean_value[(size_t)tid * NF + sel[i]];
            mx = fmaxf(mx, wv[i]);
        }
        float sum = 0.f;
        for (int i = 0; i < TOPK; ++i) { wv[i] = expf(wv[i] - mx); sum += wv[i]; }
        const float inv = 1.0f / sum;
        for (int i = 0; i < TOPK; ++i) tc_out[tid * TOPK + i] = wv[i] * inv;
    }
    if (tid < TOPK) idx_out[tid] = sel[tid];
}

// ---------------------------------------------------------------------------
// context_out: out[b,t,c] = sum_i tc[b][i] * Y[b,(t+idx[i])%L,c]
// Y bf16 (= V@(WV*Wfc)); out f32 (FINAL output — roll commutes with row-GEMM).
// ---------------------------------------------------------------------------
__global__ __launch_bounds__(256) void context_out(const unsigned short* __restrict__ Y,
                                                   const int* __restrict__ idx,
                                                   const float* __restrict__ tc,
                                                   float* __restrict__ out) {
    const size_t gid = (size_t)blockIdx.x * 256 + threadIdx.x;
    const int c8 = (int)(gid & 63);
    const int t  = (int)((gid >> 6) & 4095);
    const int b  = (int)(gid >> 18);

    __shared__ int sIdx[TOPK];
    __shared__ float sW[TOPK];
    if (threadIdx.x < TOPK) {
        sIdx[threadIdx.x] = idx[threadIdx.x];
        sW[threadIdx.x]   = tc[b * TOPK + threadIdx.x];
    }
    __syncthreads();

    const unsigned short* yb = Y + (size_t)b * L * C;
    float a[8] = {};
#pragma unroll
    for (int i = 0; i < TOPK; ++i) {
        const int row = (t + sIdx[i]) & (L - 1);
        const uint4 v = *(const uint4*)&yb[(size_t)row * C + c8 * 8];
        const float wgt = sW[i];
        a[0] += wgt * bf2f((unsigned short)(v.x & 0xFFFF));
        a[1] += wgt * bf2f((unsigned short)(v.x >> 16));
        a[2] += wgt * bf2f((unsigned short)(v.y & 0xFFFF));
        a[3] += wgt * bf2f((unsigned short)(v.y >> 16));
        a[4] += wgt * bf2f((unsigned short)(v.z & 0xFFFF));
        a[5] += wgt * bf2f((unsigned short)(v.z >> 16));
        a[6] += wgt * bf2f((unsigned short)(v.w & 0xFFFF));
        a[7] += wgt * bf2f((unsigned short)(v.w >> 16));
    }
    float* o = out + gid * 8;
    *(float4*)&o[0] = make_float4(a[0], a[1], a[2], a[3]);
    *(float4*)&o[4] = make_float4(a[4], a[5], a[6], a[7]);
}

// ---------------------------------------------------------------------------
extern "C" void kernel_launch(void* const* d_in, const int* in_sizes, int n_in,
                              void* d_out, int out_size, void* d_ws, size_t ws_size,
                              hipStream_t stream) {
    const float* Q   = (const float*)d_in[0];
    const float* K   = (const float*)d_in[1];
    const float* V   = (const float*)d_in[2];
    const float* WQ  = (const float*)d_in[4];
    const float* WK  = (const float*)d_in[5];
    const float* WV  = (const float*)d_in[6];
    const float* Wfc = (const float*)d_in[7];
    float* out = (float*)d_out;

    const size_t SZ = (size_t)B * L * C;          // 16,777,216 elements
    const size_t WSZ = 512 * 512;
    unsigned short* kTb  = (unsigned short*)d_ws; // 32 MB (B,C,L) raw-K bf16
    unsigned short* qTb  = kTb + SZ;              // 32 MB (B,C,L) G = Q@M
    unsigned short* Yb   = qTb + SZ;              // 32 MB (B,L,C) Y = V@(WV*Wfc)
    unsigned short* WQb  = Yb + SZ;               // 512 KB each
    unsigned short* WKb  = WQb + WSZ;
    unsigned short* WVb  = WKb + WSZ;
    unsigned short* Wfct = WVb + WSZ;             // Wfc^T (N x K)
    unsigned short* Mt   = Wfct + WSZ;            // Mt[e][d] = (WK WQ^T)[e,d]
    unsigned short* Nt   = Mt + WSZ;              // Nt[f][d] = (WV Wfc)[d,f]
    float* Ppart      = (float*)(Nt + WSZ);           // NBLK * 2*NF = 16 MB
    float* Pacc       = Ppart + (size_t)NBLK * 2 * NF; // B*2*NF (swizzled)
    float* mean_value = Pacc + (size_t)B * 2 * NF;    // B*NF
    float* tc         = mean_value + (size_t)B * NF;  // B*TOPK
    int*   idx        = (int*)(tc + B * TOPK);        // TOPK

    cvt_bf16_3<<<dim3(128, 1, 3), 256, 0, stream>>>(
        (const float4*)WQ, (uint4*)WQb,
        (const float4*)WK, (uint4*)WKb,
        (const float4*)WV, (uint4*)WVb);
    wtrans<<<dim3(16, 16), 256, 0, stream>>>(Wfc, Wfct);
    ktrans<<<dim3(64, 8, 8), 256, 0, stream>>>(K, kTb);

    // z=0: Mt[e][d] = sum_c WK[e,c]*WQ[d,c]
    // z=1: Nt[f][d] = sum_c Wfct[f,c]*WVb[d,c] = (WV@Wfc)[d,f]
    gemm_mini2<<<dim3(4, 4, 2), 256, 0, stream>>>(WKb, WQb, Mt, Wfct, WVb, Nt);
    // z=0: G = Q@M (TRANSOUT)   z=1: Y = V@N (row-major) — one launch
    gemm_big2<<<dim3(256, 4, 2), 256, 0, stream>>>(Q, Mt, qTb, V, Nt, Yb);

    corr_fft16<<<dim3(NBLK), 256, 0, stream>>>(qTb, kTb, Ppart);
    reduce_pacc<<<dim3(256), 256, 0, stream>>>(Ppart, Pacc);
    ifft_mean<<<dim3(B), 256, 0, stream>>>(Pacc, mean_value);
    topk_softmax<<<dim3(1), 256, 0, stream>>>(mean_value, idx, tc);

    context_out<<<dim3(8192), 256, 0, stream>>>(Yb, idx, tc, out);
}